// Round 12
// baseline (760.620 us; speedup 1.0000x reference)
//
#include <hip/hip_runtime.h>

typedef unsigned int uint;
typedef unsigned short ushort;
typedef unsigned long long u64;

#define NITEMS 50000
#define NDATA  20000
#define BLKCAP 4096u          // per-block hit region (uint entries)
#define OVCAP  65536u         // overflow region

// ---------------- ws layout (bytes) ----------------
#define OFF_LSTMOUT   0x0000000ULL  // [64][64][256] f32 = 4 MB   (memset 0: covers t>=len masking)
#define OFF_HX        0x0400000ULL  // u64[2 parity][64 item][256 j] = 256 KB (memset 0: tag 0) — LLC authoritative
#define OFF_HXM       0x0440000ULL  // u64[2 parity][64 item][256 j] = 256 KB (memset 0) — same-XCD L2 mirror
#define OFF_PACKED    0x0480000ULL  // [4096] u64 = 32 KB         (memset 0: argmax identity, bf16 pass)
#define OFF_PACKED2   0x0488000ULL  // [4096] u64 = 32 KB         (memset 0 + prep seeds zero rows)
#define OFF_HITCNTS   0x0490000ULL  // [512] uint                  (memset 0)
#define OFF_OHITCNT   0x0490800ULL  // uint                        (memset 0)
#define MEMSET_BYTES  0x0491000ULL
#define OFF_QMARGIN   0x0491000ULL  // [4096] f32 (margin, or -1e30 sentinel for zero rows)
#define OFF_XW        0x05A0000ULL  // [4096][1024] f32 = 16 MB
#define OFF_QKV       0x15A0000ULL  // [4096][768] f32 = 12 MB (cols: 0-255 q, 256-511 k, 512-767 v)
#define OFF_HITBUF    OFF_QKV       // 512*4096 uints = 8 MB; consumed by knn's INLINE rescore -> dead before qkv writes
#define OFF_WIHT      0x21A0000ULL  // [128][1024] f32 transposed W_ih
#define OFF_WQKVT     0x2220000ULL  // [256][768] f32 transposed Wq|Wk|Wv
#define OFF_BIASIH    0x22E0000ULL  // [1024] f32 (b_ih + b_hh)
#define OFF_BQKV      0x22E1000ULL  // [768] f32
#define OFF_DNSCALE   0x22E2000ULL  // [20000] f32  1/max(norm,eps)
#define OFF_AV        0x22FE000ULL  // [128][64] f32 (transposed: [e][b])
#define OFF_DEMB16    0x2306000ULL  // [20000][128] bf16 = 5.12 MB
#define OFF_A16       0x27E8000ULL  // [4096][128] bf16 = 1 MB  (emb[x], pre-posenc)
#define OFF_OVF       0x28E8000ULL  // [65536] uint overflow region = 256 KB
// end 0x2928000 = 43.2 MB

__device__ __forceinline__ ushort f2bf(float f) {
  union { float f; uint u; } v; v.f = f;
  uint u = v.u;
  return (ushort)((u + 0x7FFFu + ((u >> 16) & 1u)) >> 16);  // RNE
}
__device__ __forceinline__ uint fkey(float f) {  // monotone float->uint
  union { float f; uint u; } v; v.f = f;
  return (v.u & 0x80000000u) ? ~v.u : (v.u | 0x80000000u);
}
__device__ __forceinline__ u64 shfl_xor_u64(u64 v, int off) {
  uint lo = (uint)v, hi = (uint)(v >> 32);
  lo = (uint)__shfl_xor((int)lo, off);
  hi = (uint)__shfl_xor((int)hi, off);
  return ((u64)hi << 32) | (u64)lo;
}

typedef __attribute__((ext_vector_type(8))) short short8;   // 8 bf16 (4 VGPRs)
typedef __attribute__((ext_vector_type(4))) float floatx4;  // MFMA acc

#define R32(M) M(0) M(1) M(2) M(3) M(4) M(5) M(6) M(7) M(8) M(9) M(10) M(11) \
  M(12) M(13) M(14) M(15) M(16) M(17) M(18) M(19) M(20) M(21) M(22) M(23) \
  M(24) M(25) M(26) M(27) M(28) M(29) M(30) M(31)

// padded LDS index for h: 4-float pad between the two 128-halves (conflict-free dual-half reads)
#define HIX(j) ((j) + (((j) >> 7) << 2))

// barrier WITHOUT vmcnt drain: only LDS ordering. sched_barrier fences per rule #18.
#define LBAR() do { \
  __builtin_amdgcn_sched_barrier(0); \
  asm volatile("s_waitcnt lgkmcnt(0)" ::: "memory"); \
  __builtin_amdgcn_s_barrier(); \
  __builtin_amdgcn_sched_barrier(0); \
} while (0)

// ================= prep: norms / bf16 conversions / transposes / biases / kNN margins =================
__global__ __launch_bounds__(256) void prep_kernel(
    const int* __restrict__ x,
    const float* __restrict__ emb, const float* __restrict__ demb,
    const float* __restrict__ W_ih,
    const float* __restrict__ Wq, const float* __restrict__ Wk, const float* __restrict__ Wv,
    const float* __restrict__ b_ih, const float* __restrict__ b_hh,
    const float* __restrict__ bq, const float* __restrict__ bk, const float* __restrict__ bv,
    float* __restrict__ dnscale, ushort* __restrict__ demb16, ushort* __restrict__ a16,
    float* __restrict__ wiht, float* __restrict__ wqkvt,
    float* __restrict__ biasih, float* __restrict__ bqkv,
    float* __restrict__ qmargin, u64* __restrict__ packed2)
{
  int blk = blockIdx.x, tid = threadIdx.x;
  if (blk < 5000) {                       // 1/max(||demb_row||, eps)
    int row = blk * 4 + (tid >> 6);
    int lane = tid & 63;
    float2 d = *(const float2*)(demb + (size_t)row * 128 + lane * 2);
    float s = d.x * d.x + d.y * d.y;
    for (int off = 32; off; off >>= 1) s += __shfl_xor(s, off);
    if (lane == 0) dnscale[row] = 1.0f / fmaxf(sqrtf(s), 1e-8f);
  } else if (blk < 6250) {                // demb -> bf16
    size_t base = ((size_t)(blk - 5000) * 256 + tid) * 8;
    float4 f1 = *(const float4*)(demb + base);
    float4 f2 = *(const float4*)(demb + base + 4);
    uint4 o;
    o.x = (uint)f2bf(f1.x) | ((uint)f2bf(f1.y) << 16);
    o.y = (uint)f2bf(f1.z) | ((uint)f2bf(f1.w) << 16);
    o.z = (uint)f2bf(f2.x) | ((uint)f2bf(f2.y) << 16);
    o.w = (uint)f2bf(f2.z) | ((uint)f2bf(f2.w) << 16);
    *(uint4*)(demb16 + base) = o;
  } else if (blk < 6506) {                // emb[x] rows -> bf16 (initial_embs, pre-posenc)
    int idx = (blk - 6250) * 256 + tid;   // < 65536
    int m = idx >> 4, seg = idx & 15;
    const float* src = emb + (size_t)x[m] * 128 + seg * 8;
    float4 f1 = *(const float4*)(src);
    float4 f2 = *(const float4*)(src + 4);
    uint4 o;
    o.x = (uint)f2bf(f1.x) | ((uint)f2bf(f1.y) << 16);
    o.y = (uint)f2bf(f1.z) | ((uint)f2bf(f1.w) << 16);
    o.z = (uint)f2bf(f2.x) | ((uint)f2bf(f2.y) << 16);
    o.w = (uint)f2bf(f2.z) | ((uint)f2bf(f2.w) << 16);
    *(uint4*)(a16 + (size_t)m * 128 + seg * 8) = o;
  } else if (blk < 7018) {                // W_ih (1024,128) -> [e][r]
    int f = (blk - 6506) * 256 + tid;
    int r = f >> 7, e = f & 127;
    wiht[e * 1024 + r] = W_ih[f];
  } else if (blk < 7786) {                // Wq/Wk/Wv (256,256) -> [e][w*256+r]
    int f = (blk - 7018) * 256 + tid;
    int w = f >> 16; int rem = f & 65535;
    int r = rem >> 8, e = rem & 255;
    const float* src = (w == 0) ? Wq : (w == 1) ? Wk : Wv;
    wqkvt[e * 768 + w * 256 + r] = src[rem];
  } else if (blk < 7790) {
    int idx = (blk - 7786) * 256 + tid;
    if (idx < 1024) biasih[idx] = b_ih[idx] + b_hh[idx];
  } else if (blk < 7793) {
    int idx = (blk - 7790) * 256 + tid;
    if (idx < 768) {
      int w = idx >> 8; int r = idx & 255;
      const float* src = (w == 0) ? bq : (w == 1) ? bk : bv;
      bqkv[idx] = src[r];
    }
  } else {                                // kNN margin per query row + zero-row seeds
    int row = (blk - 7793) * 4 + (tid >> 6);   // 1024 blocks -> 4096 rows
    int lane = tid & 63;
    float2 d = *(const float2*)(emb + (size_t)x[row] * 128 + lane * 2);
    float s = d.x * d.x + d.y * d.y;
    for (int off = 32; off; off >>= 1) s += __shfl_xor(s, off);
    if (lane == 0) {
      if (s == 0.f) {
        qmargin[row] = -1e30f;            // sentinel: thr = best+1e30 -> no hits ever
        // all sims exactly +0 -> argmax = first index (n=0), exact
        packed2[row] = ((u64)fkey(0.0f) << 32) | 0xFFFFFFFFull;
      } else {
        // PROVABLE bound: |sim_bf16 - sim_exact| <= 2*2^-8*||q|| (q AND d rounding,
        // Cauchy-Schwarz) ~= 0.0157||q||; 0.017||q|| adds fp32-accum slack.
        qmargin[row] = 0.017f * sqrtf(s) + 1e-5f;
      }
    }
  }
}

// ================= xW = (emb[x]+posenc) @ W_ih^T + (b_ih+b_hh) =================
__global__ __launch_bounds__(256) void xw_kernel(
    const int* __restrict__ x, const float* __restrict__ emb,
    const float* __restrict__ wiht, const float* __restrict__ biasih,
    float* __restrict__ xW)
{
  __shared__ __align__(16) float At[128 * 16];   // [e][m]
  int blk = blockIdx.x, tid = threadIdx.x;
  int m0 = blk * 16;
  for (int c = 0; c < 8; ++c) {
    int idx = c * 256 + tid;
    int mm = idx >> 7, e = idx & 127;
    int m = m0 + mm;
    int bcol = m & 63;                 // PositionalEncoding indexed by BATCH (faithful quirk)
    int xv = x[m];
    float val = emb[(size_t)xv * 128 + e];
    int j = e >> 1;
    float arg = (float)bcol * __expf((float)j * -0.14391157f);  // exp(-j*ln(10000)/64)
    val += (e & 1) ? cosf(arg) : sinf(arg);
    At[e * 16 + mm] = val;
  }
  __syncthreads();
  int quad = tid >> 6, l = tid & 63;
  for (int rp = 0; rp < 4; ++rp) {
    int r = rp * 256 + l * 4;
    float acc[4][4] = {};
    for (int e = 0; e < 128; ++e) {
      float4 wv4 = *(const float4*)(wiht + e * 1024 + r);
      float4 av4 = *(const float4*)(At + e * 16 + quad * 4);
      float am[4] = {av4.x, av4.y, av4.z, av4.w};
      float wr4[4] = {wv4.x, wv4.y, wv4.z, wv4.w};
      #pragma unroll
      for (int mi = 0; mi < 4; ++mi)
        #pragma unroll
        for (int ri = 0; ri < 4; ++ri)
          acc[mi][ri] += am[mi] * wr4[ri];
    }
    float4 bv4 = *(const float4*)(biasih + r);
    #pragma unroll
    for (int mi = 0; mi < 4; ++mi) {
      size_t m = (size_t)(m0 + quad * 4 + mi);
      float4 o;
      o.x = acc[mi][0] + bv4.x; o.y = acc[mi][1] + bv4.y;
      o.z = acc[mi][2] + bv4.z; o.w = acc[mi][3] + bv4.w;
      *(float4*)(xW + m * 1024 + r) = o;
    }
  }
}

// ================= FUSED lstm + knn (round 12): knn staging DELETED.
// Round-11 post-mortem: fusion is a wash because knn throughput scales with
// allocated wave slots; the lever is knn per-slot efficiency (MfmaUtil 6.9%,
// ~70% stall cycles). Key observation: the LDS staging was a PURE COPY —
// bsh[(ns*16+col)*144 + kf*32 + quad*8] is byte-identical to
// demb16[n*128 + kf*32 + quad*8]. So B-fragments now load DIRECTLY from
// global (demb16 is L3-resident; per-iter working set 16KB shared by all 8
// waves -> L1 hits; 16 outstanding 16B loads/wave hide L2 latency under
// MFMAs). Deletes: b_sh (36KB LDS), double-buffer, prefetch, 2 barriers/iter
// x 80 iters. OOB rows clamp to NDATA-1 (finite bf16; sims still masked by
// valid/sc=0 — superset proof unchanged). lstm body byte-identical round-4. =================
__global__ __launch_bounds__(512, 2) void lstm_knn_kernel(
    const int* __restrict__ lengths, const float* __restrict__ Whh,
    const float* __restrict__ xW, float* __restrict__ lstm_out,
    u64* __restrict__ hx, u64* __restrict__ hxm,
    const ushort* __restrict__ a16, const ushort* __restrict__ demb16,
    const float* __restrict__ dnscale, const float* __restrict__ qmargin,
    u64* __restrict__ packed, uint* __restrict__ hitcnts, uint* __restrict__ ohitcnt,
    uint* __restrict__ hitbuf, uint* __restrict__ ovbuf,
    const int* __restrict__ x, const float* __restrict__ emb,
    const float* __restrict__ demb, u64* __restrict__ packed2)
{
  __shared__ __align__(16) float h_sh[264];      // lstm: 2x128 + pad
  __shared__ float part_sh[256];                 // lstm
  __shared__ uint lcnt;                          // knn
  int tid = threadIdx.x;

  if (blockIdx.x < 256) {
    // ==================== LSTM body (exact round-4) ====================
    int blk = blockIdx.x;
    int b = blk & 63, q = blk >> 6;          // item b blocks {b,64+b,128+b,192+b}
    int row_local = tid >> 1, half = tid & 1;
    int gate = row_local >> 6, jloc = row_local & 63;
    int grow = gate * 256 + q * 64 + jloc;
    const float4* wp4 = (const float4*)(Whh + (size_t)grow * 256 + half * 128);
#define WDECL(i) float4 tt##i = wp4[i]; \
  float w##i##x = tt##i.x, w##i##y = tt##i.y, w##i##z = tt##i.z, w##i##w = tt##i.w;
    R32(WDECL)
    // pin: asm-produced values cannot be rematerialized -> loads can't sink into the loop
#define WPIN(i) asm volatile("" : "+v"(w##i##x), "+v"(w##i##y), "+v"(w##i##z), "+v"(w##i##w));
    R32(WPIN)
    int len = lengths[b];
    if (tid < 256) h_sh[HIX(tid)] = 0.f;
    float cval = 0.f;
    // poller mapping: tid in [320,512) -> the 192 remote j (skip own quarter)
    int prm = tid - 320;
    int jr = (prm < q * 64) ? prm : prm + 64;
    bool fast_ok = true;
    int j1 = q * 64 + (tid - 64);            // wave-1 deferred-store lane -> j
    // xW preload for t=0 (wave0)
    float xw0 = 0.f, xw1 = 0.f, xw2 = 0.f, xw3 = 0.f;
    if (tid < 64) {
      const float* xwrow = xW + ((size_t)0 * 64 + b) * 1024 + q * 64 + tid;
      xw0 = xwrow[0]; xw1 = xwrow[256]; xw2 = xwrow[512]; xw3 = xwrow[768];
    }
    __syncthreads();
    for (int t = 0; t < len; ++t) {
      // prefetch xW(t+1) (wave0): retires under matmul+phase1
      float nx0 = 0.f, nx1 = 0.f, nx2 = 0.f, nx3 = 0.f;
      if (tid < 64 && t + 1 < len) {
        const float* xwrow = xW + ((size_t)(t + 1) * 64 + b) * 1024 + q * 64 + tid;
        nx0 = xwrow[0]; nx1 = xwrow[256]; nx2 = xwrow[512]; nx3 = xwrow[768];
      }
      // wave1: snapshot h(t-1) BEFORE wave0 overwrites it (pre-barrier = race-free)
      float hprev = 0.f;
      if (tid >= 64 && tid < 128 && t > 0) hprev = h_sh[HIX(j1)];
      const float4* h4 = (const float4*)(h_sh + half * 132);
      float a[4] = {0.f, 0.f, 0.f, 0.f};
#define WACC(i) { float4 hv_ = h4[i]; \
    a[(i) & 3] += w##i##x * hv_.x + w##i##y * hv_.y + w##i##z * hv_.z + w##i##w * hv_.w; }
      R32(WACC)
      float acc = (a[0] + a[2]) + (a[1] + a[3]);
      acc += __shfl_xor(acc, 1);             // combine the two half-rows in-register
      if (!half) part_sh[row_local] = acc;
      LBAR();
      if (tid < 64) {
        // -------- phase 2 (wave 0): gates -> h, publish mirror + authoritative --------
        float gi = part_sh[tid]       + xw0;
        float gf = part_sh[64 + tid]  + xw1;
        float gg = part_sh[128 + tid] + xw2;
        float go = part_sh[192 + tid] + xw3;
        float ii = 1.f / (1.f + __expf(-gi));
        float ff = 1.f / (1.f + __expf(-gf));
        float oo = 1.f / (1.f + __expf(-go));
        float tg = 1.f - 2.f / (1.f + __expf(2.f * gg));
        cval = ff * cval + ii * tg;
        float tc = 1.f - 2.f / (1.f + __expf(2.f * cval));
        float hv = oo * tc;
        int j = q * 64 + tid;
        union { float f; uint u; } cu; cu.f = hv;
        u64 pk = ((u64)cu.u << 32) | (u64)(uint)(t + 1);
        size_t slot = ((size_t)((t + 1) & 1) * 64 + b) * 256 + j;
        // same-slot ordering guard: drain all stores older than the 4 prefetch loads
        __builtin_amdgcn_sched_barrier(0);
        asm volatile("s_waitcnt vmcnt(4)" ::: "memory");
        asm volatile("global_store_dwordx2 %0, %1, off"
                     :: "v"(hxm + slot), "v"(pk) : "memory");
        __hip_atomic_store(hx + slot, pk, __ATOMIC_RELAXED, __HIP_MEMORY_SCOPE_AGENT);
        h_sh[HIX(j)] = hv;                   // own quarter stays local
        xw0 = nx0; xw1 = nx1; xw2 = nx2; xw3 = nx3;
      } else if (tid < 128) {
        // -------- wave 1: deferred lstm_out store (one iter late; no in-kernel reader) --------
        if (t > 0) lstm_out[((size_t)b * 64 + (t - 1)) * 256 + j1] = hprev;
      } else if (tid >= 320 && t + 1 < len) {
        // -------- pollers (waves 5-7): fetch partners' h(t+1), overlapped with phase 2 --------
        size_t slot = ((size_t)((t + 1) & 1) * 64 + b) * 256 + jr;
        uint want = (uint)(t + 1);
        u64 v = 0;
        bool got = false;
        if (fast_ok) {
          const u64* ms = hxm + slot;
          for (int tries = 0; tries < 32; ++tries) {
            asm volatile("global_load_dwordx2 %0, %1, off sc0\n\t"
                         "s_waitcnt vmcnt(0)"
                         : "=&v"(v) : "v"(ms) : "memory");
            if ((uint)v == want) { got = true; break; }
          }
          if (!got && t > 0) fast_ok = false;   // sticky fallback; t==0 may be launch skew
        }
        if (!got) {
          const u64* as = hx + slot;            // authoritative, published in-phase by wave0
          int guard = 0;
          while (true) {
            v = __hip_atomic_load(as, __ATOMIC_RELAXED, __HIP_MEMORY_SCOPE_AGENT);
            if ((uint)v == want || ++guard > (1 << 24)) break;
          }
        }
        union { uint u; float f; } cv; cv.u = (uint)(v >> 32);
        h_sh[HIX(jr)] = cv.f;
      }
      LBAR();                                // h_sh (own + remote) complete before next matmul
    }
    // final lstm_out row (wave1 covered only up to t=len-2)
    if (tid >= 64 && tid < 128) {
      float hl = h_sh[HIX(j1)];
      lstm_out[((size_t)b * 64 + (len - 1)) * 256 + j1] = hl;
    }
    return;
  }

  // ==================== kNN body (direct-global B, no staging, 2 chunks/block) ====================
  int nb = blockIdx.x - 256;               // 0..255
  int mt = nb >> 3;                        // 32 m-tiles
  int cpair = nb & 7;                      // 8 chunk-pairs
  int w8 = tid >> 6;                       // wave 0..7
  int s = w8 >> 2, wv2 = w8 & 3;           // s-slice + quarter
  int lane = tid & 63;
  int col = lane & 15, quad = lane >> 4;
  int M0 = mt * 128;
  short8 afrag[4];
  {
    int mrow = M0 + s * 64 + wv2 * 16 + col;
    #pragma unroll
    for (int kf = 0; kf < 4; ++kf)
      afrag[kf] = *(const short8*)(a16 + (size_t)mrow * 128 + kf * 32 + quad * 8);
  }
  float qm[4];
  #pragma unroll
  for (int r = 0; r < 4; ++r)
    qm[r] = qmargin[M0 + s * 64 + wv2 * 16 + quad * 4 + r];
  const int niter = 20;                    // ceil(1250/64)

  for (int c2 = 0; c2 < 2; ++c2) {
    int chunk = cpair * 2 + c2;
    int kb = mt * 16 + chunk;              // original hit-region index
    int nbase = chunk * 1250, nend = nbase + 1250;
    if (tid == 0) lcnt = 0;
    __syncthreads();                       // lcnt reset visible before sweep-B atomics
    float best[4] = {-1e30f, -1e30f, -1e30f, -1e30f};
    int bidx[4] = {};

    // ================== SWEEP A: pure argmax, B direct from global ==================
    for (int it = 0; it < niter; ++it) {
      int n0 = nbase + it * 64;
      #pragma unroll
      for (int ns = 0; ns < 4; ++ns) {
        int n = n0 + ns * 16 + col;
        bool valid = (n < nend);
        int nc = valid ? n : (NDATA - 1);  // clamp: stays inside demb16 (finite bf16)
        const ushort* bp = demb16 + (size_t)nc * 128 + quad * 8;
        float sc = valid ? dnscale[n] : 0.f;
        floatx4 acc = {0.f, 0.f, 0.f, 0.f};
        acc = __builtin_amdgcn_mfma_f32_16x16x32_bf16(afrag[0], *(const short8*)(bp),      acc, 0, 0, 0);
        acc = __builtin_amdgcn_mfma_f32_16x16x32_bf16(afrag[1], *(const short8*)(bp + 32), acc, 0, 0, 0);
        acc = __builtin_amdgcn_mfma_f32_16x16x32_bf16(afrag[2], *(const short8*)(bp + 64), acc, 0, 0, 0);
        acc = __builtin_amdgcn_mfma_f32_16x16x32_bf16(afrag[3], *(const short8*)(bp + 96), acc, 0, 0, 0);
        #pragma unroll
        for (int r = 0; r < 4; ++r) {        // D[row=quad*4+r][col=lane&15]
          float sim = acc[r] * sc;
          if (valid && sim > best[r]) { best[r] = sim; bidx[r] = n; }
        }
      }
    }
    // chunk-final per-row best (butterfly over the 16 col lanes) + global argmax output
    float thr[4];
    #pragma unroll
    for (int r = 0; r < 4; ++r) {
      u64 p = ((u64)fkey(best[r]) << 32) | (u64)(0xFFFFFFFFu - (uint)bidx[r]);
      #pragma unroll
      for (int off = 1; off < 16; off <<= 1) {   // col bits only: stays in row group
        u64 o = shfl_xor_u64(p, off);
        if (o > p) p = o;
      }
      int m = M0 + s * 64 + wv2 * 16 + quad * 4 + r;
      union { uint u; float f; } bu;
      uint k = (uint)(p >> 32);
      bu.u = (k & 0x80000000u) ? (k & 0x7FFFFFFFu) : ~k;   // unfkey
      thr[r] = bu.f - qm[r];
      if (col == 0)
        atomicMax((unsigned long long*)&packed[m], (unsigned long long)p);
    }

    // ================== SWEEP B: record candidates >= thr (per-chunk region) ==================
    uint* myregion = hitbuf + (size_t)kb * BLKCAP;
    uint* ovregion = ovbuf;
    for (int it = 0; it < niter; ++it) {
      int n0 = nbase + it * 64;
      #pragma unroll
      for (int ns = 0; ns < 4; ++ns) {
        int n = n0 + ns * 16 + col;
        bool valid = (n < nend);
        int nc = valid ? n : (NDATA - 1);
        const ushort* bp = demb16 + (size_t)nc * 128 + quad * 8;
        float sc = valid ? dnscale[n] : 0.f;
        floatx4 acc = {0.f, 0.f, 0.f, 0.f};
        acc = __builtin_amdgcn_mfma_f32_16x16x32_bf16(afrag[0], *(const short8*)(bp),      acc, 0, 0, 0);
        acc = __builtin_amdgcn_mfma_f32_16x16x32_bf16(afrag[1], *(const short8*)(bp + 32), acc, 0, 0, 0);
        acc = __builtin_amdgcn_mfma_f32_16x16x32_bf16(afrag[2], *(const short8*)(bp + 64), acc, 0, 0, 0);
        acc = __builtin_amdgcn_mfma_f32_16x16x32_bf16(afrag[3], *(const short8*)(bp + 96), acc, 0, 0, 0);
        #pragma unroll
        for (int r = 0; r < 4; ++r) {
          float sim = acc[r] * sc;
          bool hit = valid && (sim >= thr[r]);   // ~2e-3 probability
          u64 mask = __ballot(hit);
          if (mask) {
            uint lcntv = (uint)__popcll(mask);
            int leader = __ffsll((unsigned long long)mask) - 1;
            uint base = 0;
            if (lane == leader) base = atomicAdd(&lcnt, lcntv);   // LDS atomic: fast
            base = (uint)__shfl((int)base, leader);
            if (hit) {
              uint pos = base + (uint)__popcll(mask & ((1ull << lane) - 1ull));
              uint mm = (uint)(M0 + s * 64 + wv2 * 16 + quad * 4 + r);
              uint rec = (mm << 15) | (uint)n;
              if (pos < BLKCAP) {
                myregion[pos] = rec;
              } else {                               // rare spill
                uint op = atomicAdd(ohitcnt, 1u);
                if (op < OVCAP) ovregion[op] = rec;
              }
            }
          }
        }
      }
    }
    __syncthreads();                       // full drain: myregion stores visible block-wide
    if (tid == 0) hitcnts[kb] = lcnt;
    // ================== INLINE RESCORE of this chunk's hit region ==================
    uint rcnt = lcnt; if (rcnt > BLKCAP) rcnt = BLKCAP;
    for (uint h = tid; h < rcnt; h += 512) {
      uint rec = myregion[h];
      uint m = rec >> 15, n = rec & 0x7FFFu;
      if (m >= 4096 || n >= NDATA) continue;
      const float* qr = emb + (size_t)x[m] * 128;
      const float* dr = demb + (size_t)n * 128;
      double p = 0.0;
      #pragma unroll 8
      for (int e = 0; e < 128; e += 2) {
        float2 qv = *(const float2*)(qr + e);
        float2 dv = *(const float2*)(dr + e);
        p += (double)qv.x * (double)dv.x + (double)qv.y * (double)dv.y;
      }
      float sx = (float)(p * (double)dnscale[n]);
      u64 key = ((u64)fkey(sx) << 32) | (u64)(0xFFFFFFFFu - n);
      atomicMax((unsigned long long*)&packed2[m], (unsigned long long)key);
    }
    __syncthreads();                       // all lcnt reads done before next chunk resets it
  }
}

// ================= fused post: blocks 0-255 qkv projection; 256-271 bf16-winner
// exact fallback; 272-287 overflow-region rescore. =================
__global__ __launch_bounds__(256) void fused_post_kernel(
    const float* __restrict__ lstm_out, const float* __restrict__ wqkvt,
    const float* __restrict__ bqkv, float* __restrict__ qkv,
    const u64* __restrict__ packed, const uint* __restrict__ ohitcnt,
    const uint* __restrict__ ovbuf, const int* __restrict__ x,
    const float* __restrict__ emb, const float* __restrict__ demb,
    const float* __restrict__ dnscale, u64* __restrict__ packed2)
{
  __shared__ __align__(16) float At[256 * 16];   // [e][m] (qkv path)
  int blk = blockIdx.x, tid = threadIdx.x;
  if (blk < 256) {                             // ---- qkv = lstm_out @ W{q,k,v}^T + bias ----
    int m0 = blk * 16;
    for (int c = 0; c < 16; ++c)
      At[tid * 16 + c] = lstm_out[((size_t)m0 + c) * 256 + tid];
    __syncthreads();
    int quad = tid >> 6, l = tid & 63;
    for (int rp = 0; rp < 3; ++rp) {
      int r = rp * 256 + l * 4;
      float acc[4][4] = {};
      for (int e = 0; e < 256; ++e) {
        float4 wv4 = *(const float4*)(wqkvt + (size_t)e * 768 + r);
        float4 av4 = *(const float4*)(At + e * 16 + quad * 4);
        float am[4] = {av4.x, av4.y, av4.z, av4.w};
        float wr4[4] = {wv4.x, wv4.y, wv4.z, wv4.w};
        #pragma unroll
        for (int mi = 0; mi < 4; ++mi)
          #pragma unroll
          for (int ri = 0; ri < 4; ++ri)
            acc[mi][ri] += am[mi] * wr4[ri];
      }
      float4 bv4 = *(const float4*)(bqkv + r);
      #pragma unroll
      for (int mi = 0; mi < 4; ++mi) {
        size_t m = (size_t)(m0 + quad * 4 + mi);
        float4 o;
        o.x = acc[mi][0] + bv4.x; o.y = acc[mi][1] + bv4.y;
        o.z = acc[mi][2] + bv4.z; o.w = acc[mi][3] + bv4.w;
        *(float4*)(qkv + m * 768 + r) = o;
      }
    }
    return;
  }
  if (blk < 272) {                             // ---- guaranteed fallback: bf16 winner exact ----
    uint m = (uint)(blk - 256) * 256 + tid;    // 0..4095
    uint n = 0xFFFFFFFFu - (uint)(packed[m] & 0xFFFFFFFFull);
    if (n < NDATA) {
      const float* qr = emb + (size_t)x[m] * 128;
      const float* dr = demb + (size_t)n * 128;
      double p = 0.0;
      #pragma unroll 8
      for (int e = 0; e < 128; e += 2) {
        float2 qv = *(const float2*)(qr + e);
        float2 dv = *(const float2*)(dr + e);
        p += (double)qv.x * (double)dv.x + (double)qv.y * (double)dv.y;
      }
      float sx = (float)(p * (double)dnscale[n]);
      u64 key = ((u64)fkey(sx) << 32) | (u64)(0xFFFFFFFFu - n);
      atomicMax((unsigned long long*)&packed2[m], (unsigned long long)key);
    }
    return;
  }
  // ---- overflow region rescore (blocks 272-287) ----
  uint cnt = *ohitcnt; if (cnt > OVCAP) cnt = OVCAP;
  for (uint h = (uint)(blk - 272) * 256 + tid; h < cnt; h += 16 * 256) {
    uint rec = ovbuf[h];
    uint m = rec >> 15, n = rec & 0x7FFFu;
    if (m >= 4096 || n >= NDATA) continue;
    const float* qr = emb + (size_t)x[m] * 128;
    const float* dr = demb + (size_t)n * 128;
    double p = 0.0;
    #pragma unroll 8
    for (int e = 0; e < 128; e += 2) {
      float2 qv = *(const float2*)(qr + e);
      float2 dv = *(const float2*)(dr + e);
      p += (double)qv.x * (double)dv.x + (double)qv.y * (double)dv.y;
    }
    float sx = (float)(p * (double)dnscale[n]);
    u64 key = ((u64)fkey(sx) << 32) | (u64)(0xFFFFFFFFu - n);
    atomicMax((unsigned long long*)&packed2[m], (unsigned long long)key);
  }
}

// ================= attention (closest fused in: attn block b needs only
// closest[b], computed here in-register) =================
__global__ __launch_bounds__(256) void attn_kernel(
    const float* __restrict__ qkv, const int* __restrict__ lengths,
    const u64* __restrict__ packed2, const float* __restrict__ demb,
    const float* __restrict__ W_out, const float* __restrict__ b_out,
    float* __restrict__ av)
{
  __shared__ float k_sh[64 * 257];               // stride 257 -> conflict-free row reads
  __shared__ __align__(16) float q_sh[4 * 256];
  __shared__ float wpart[4 * 64];
  __shared__ float wtot[64];
  __shared__ float out_sh[256];
  int b = blockIdx.x, tid = threadIdx.x;
  int wv = tid >> 6, lane = tid & 63;
  int len = lengths[b];
  for (int s = 0; s < 64; ++s)
    k_sh[s * 257 + tid] = qkv[((size_t)b * 64 + s) * 768 + 256 + tid];
  // ---- closest (this block's b only), in-register: same-thread write/read ----
  float clv = 0.f;
  if (tid < 128) {
    float sum = 0.f;
    for (int t = 0; t < 64; ++t) {
      uint low = (uint)(packed2[t * 64 + b] & 0xFFFFFFFFull);
      uint n = 0xFFFFFFFFu - low;
      if (n >= NDATA) n = 0;               // safety clamp: never page-fault
      sum += demb[(size_t)n * 128 + tid];
    }
    clv = sum * (1.0f / 64.0f);
  }
  wpart[tid] = 0.f;
  for (int tq = 0; tq < 16; ++tq) {
    __syncthreads();
    #pragma unroll
    for (int c = 0; c < 4; ++c)
      q_sh[c * 256 + tid] = qkv[((size_t)b * 64 + tq * 4 + c) * 768 + tid];
    __syncthreads();
    const float* krow = k_sh + lane * 257;
    const float* qrow = q_sh + wv * 256;
    float sc = 0.f;
    #pragma unroll 8
    for (int h = 0; h < 256; ++h)
      sc += qrow[h] * krow[h];
    sc *= 0.0625f;                         // 1/sqrt(256)
    bool vs = (lane < len);                // key-position mask
    float scm = vs ? sc : -1e30f;
    float mx = scm;
    for (int off = 32; off; off >>= 1) mx = fmaxf(mx, __shfl_xor(mx, off));
    float e = vs ? __expf(sc - mx) : 0.f;
    float sum = e;
    for (int off = 32; off; off >>= 1) sum += __shfl_xor(sum, off);
    wpart[wv * 64 + lane] += e / sum;
  }
  __syncthreads();
  if (tid < 64)
    wtot[tid] = (wpart[tid] + wpart[64 + tid] + wpart[128 + tid] + wpart[192 + tid]) * (1.0f / 64.0f);
  __syncthreads();
  {
    float acc = 0.f;
    for (int s = 0; s < 64; ++s)
      acc += wtot[s] * qkv[((size_t)b * 64 + s) * 768 + 512 + tid];
    out_sh[tid] = acc;
  }
  __syncthreads();
  if (tid < 128) {
    const float4* wr = (const float4*)(W_out + (size_t)tid * 256);
    float p = b_out[tid];
    #pragma unroll
    for (int c = 0; c < 64; ++c) {
      float4 u = wr[c];
      p += out_sh[c * 4 + 0] * u.x + out_sh[c * 4 + 1] * u.y
         + out_sh[c * 4 + 2] * u.z + out_sh[c * 4 + 3] * u.w;
    }
    av[tid * 64 + b] = p * clv;            // [e][b] for wave-uniform loads later
  }
}

// ================= out[b][i] = av[:,b] . emb_table[i] =================
__global__ __launch_bounds__(256) void final_kernel(
    const float* __restrict__ emb, const float* __restrict__ av,
    float* __restrict__ out)
{
  int i = blockIdx.x * 256 + threadIdx.x;
  if (i >= NITEMS) return;
  const float4* row = (const float4*)(emb + (size_t)i * 128);
  float acc[64];
  #pragma unroll
  for (int bb = 0; bb < 64; ++bb) acc[bb] = 0.f;
  for (int e4 = 0; e4 < 32; ++e4) {
    float4 u = row[e4];
    float wvv[4] = {u.x, u.y, u.z, u.w};
    const float* ab = av + e4 * 4 * 64;    // wave-uniform addresses -> scalar pipe
    #pragma unroll
    for (int j = 0; j < 4; ++j) {
      #pragma unroll
      for (int bb = 0; bb < 64; ++bb)
        acc[bb] += wvv[j] * ab[j * 64 + bb];
    }
  }
  #pragma unroll
  for (int bb = 0; bb < 64; ++bb)
    out[(size_t)bb * NITEMS + i] = acc[bb];
}

// ================= launch =================
extern "C" void kernel_launch(void* const* d_in, const int* in_sizes, int n_in,
                              void* d_out, int out_size, void* d_ws, size_t ws_size,
                              hipStream_t stream)
{
  const int*   x       = (const int*)d_in[0];
  const int*   lengths = (const int*)d_in[1];
  const float* emb     = (const float*)d_in[2];
  const float* demb    = (const float*)d_in[3];
  const float* W_ih    = (const float*)d_in[4];
  const float* W_hh    = (const float*)d_in[5];
  const float* b_ih    = (const float*)d_in[6];
  const float* b_hh    = (const float*)d_in[7];
  const float* Wq      = (const float*)d_in[8];
  const float* bq      = (const float*)d_in[9];
  const float* Wk      = (const float*)d_in[10];
  const float* bk      = (const float*)d_in[11];
  const float* Wv      = (const float*)d_in[12];
  const float* bv      = (const float*)d_in[13];
  const float* W_out   = (const float*)d_in[14];
  const float* b_out   = (const float*)d_in[15];

  char* ws = (char*)d_ws;
  float*  lstm_out = (float*)(ws + OFF_LSTMOUT);
  u64*    hx       = (u64*)(ws + OFF_HX);
  u64*    hxm      = (u64*)(ws + OFF_HXM);
  u64*    packed   = (u64*)(ws + OFF_PACKED);
  u64*    packed2  = (u64*)(ws + OFF_PACKED2);
  uint*   hitcnts  = (uint*)(ws + OFF_HITCNTS);
  uint*   ohitcnt  = (uint*)(ws + OFF_OHITCNT);
  float*  qmargin  = (float*)(ws + OFF_QMARGIN);
  uint*   hitbuf   = (uint*)(ws + OFF_HITBUF);
  uint*   ovbuf    = (uint*)(ws + OFF_OVF);
  float*  xW       = (float*)(ws + OFF_XW);
  float*  qkv      = (float*)(ws + OFF_QKV);
  float*  wiht     = (float*)(ws + OFF_WIHT);
  float*  wqkvt    = (float*)(ws + OFF_WQKVT);
  float*  biasih   = (float*)(ws + OFF_BIASIH);
  float*  bqkv     = (float*)(ws + OFF_BQKV);
  float*  dnscale  = (float*)(ws + OFF_DNSCALE);
  float*  av       = (float*)(ws + OFF_AV);
  ushort* demb16   = (ushort*)(ws + OFF_DEMB16);
  ushort* a16      = (ushort*)(ws + OFF_A16);

  hipMemsetAsync(d_ws, 0, (size_t)MEMSET_BYTES, stream);

  hipLaunchKernelGGL(prep_kernel, dim3(8817), dim3(256), 0, stream,
                     x, emb, demb, W_ih, Wq, Wk, Wv, b_ih, b_hh, bq, bk, bv,
                     dnscale, demb16, a16, wiht, wqkvt, biasih, bqkv,
                     qmargin, packed2);
  hipLaunchKernelGGL(xw_kernel, dim3(256), dim3(256), 0, stream,
                     x, emb, wiht, biasih, xW);
  hipLaunchKernelGGL(lstm_knn_kernel, dim3(512), dim3(512), 0, stream,
                     lengths, W_hh, xW, lstm_out, hx, hxm,
                     a16, demb16, dnscale, qmargin, packed, hitcnts, ohitcnt,
                     hitbuf, ovbuf, x, emb, demb, packed2);
  hipLaunchKernelGGL(fused_post_kernel, dim3(288), dim3(256), 0, stream,
                     lstm_out, wqkvt, bqkv, qkv, packed, ohitcnt, ovbuf,
                     x, emb, demb, dnscale, packed2);
  hipLaunchKernelGGL(attn_kernel, dim3(64), dim3(256), 0, stream,
                     qkv, lengths, packed2, demb, W_out, b_out, av);
  hipLaunchKernelGGL(final_kernel, dim3(196), dim3(256), 0, stream,
                     emb, av, (float*)d_out);
}

// Round 13
// 593.513 us; speedup vs baseline: 1.2816x; 1.2816x over previous
//
#include <hip/hip_runtime.h>

typedef unsigned int uint;
typedef unsigned short ushort;
typedef unsigned long long u64;

#define NITEMS 50000
#define NDATA  20000
#define BLKCAP 4096u          // per-block hit region (uint entries)
#define OVCAP  65536u         // overflow region

// ---------------- ws layout (bytes) ----------------
#define OFF_LSTMOUT   0x0000000ULL  // [64][64][256] f32 = 4 MB   (memset 0: covers t>=len masking)
#define OFF_HX        0x0400000ULL  // u64[2 parity][64 item][256 j] = 256 KB (memset 0: tag 0) — LLC authoritative
#define OFF_HXM       0x0440000ULL  // u64[2 parity][64 item][256 j] = 256 KB (memset 0) — same-XCD L2 mirror
#define OFF_PACKED    0x0480000ULL  // [4096] u64 = 32 KB         (memset 0: argmax identity, bf16 pass)
#define OFF_PACKED2   0x0488000ULL  // [4096] u64 = 32 KB         (memset 0 + prep seeds zero rows)
#define OFF_HITCNTS   0x0490000ULL  // [512] uint                  (memset 0)
#define OFF_OHITCNT   0x0490800ULL  // uint                        (memset 0)
#define MEMSET_BYTES  0x0491000ULL
#define OFF_QMARGIN   0x0491000ULL  // [4096] f32 (margin, or -1e30 sentinel for zero rows)
#define OFF_XW        0x05A0000ULL  // [4096][1024] f32 = 16 MB
#define OFF_QKV       0x15A0000ULL  // [4096][768] f32 = 12 MB (cols: 0-255 q, 256-511 k, 512-767 v)
#define OFF_HITBUF    OFF_QKV       // 512*4096 uints = 8 MB; consumed by knn's INLINE rescore -> dead before qkv writes
#define OFF_WIHT      0x21A0000ULL  // [128][1024] f32 transposed W_ih
#define OFF_WQKVT     0x2220000ULL  // [256][768] f32 transposed Wq|Wk|Wv
#define OFF_BIASIH    0x22E0000ULL  // [1024] f32 (b_ih + b_hh)
#define OFF_BQKV      0x22E1000ULL  // [768] f32
#define OFF_DNSCALE   0x22E2000ULL  // [20000] f32  1/max(norm,eps)
#define OFF_AV        0x22FE000ULL  // [128][64] f32 (transposed: [e][b])
#define OFF_DEMB16    0x2306000ULL  // [20000][128] bf16 = 5.12 MB
#define OFF_A16       0x27E8000ULL  // [4096][128] bf16 = 1 MB  (emb[x], pre-posenc)
#define OFF_OVF       0x28E8000ULL  // [65536] uint overflow region = 256 KB
// end 0x2928000 = 43.2 MB

__device__ __forceinline__ ushort f2bf(float f) {
  union { float f; uint u; } v; v.f = f;
  uint u = v.u;
  return (ushort)((u + 0x7FFFu + ((u >> 16) & 1u)) >> 16);  // RNE
}
__device__ __forceinline__ uint fkey(float f) {  // monotone float->uint
  union { float f; uint u; } v; v.f = f;
  return (v.u & 0x80000000u) ? ~v.u : (v.u | 0x80000000u);
}
__device__ __forceinline__ u64 shfl_xor_u64(u64 v, int off) {
  uint lo = (uint)v, hi = (uint)(v >> 32);
  lo = (uint)__shfl_xor((int)lo, off);
  hi = (uint)__shfl_xor((int)hi, off);
  return ((u64)hi << 32) | (u64)lo;
}

typedef __attribute__((ext_vector_type(8))) short short8;   // 8 bf16 (4 VGPRs)
typedef __attribute__((ext_vector_type(4))) float floatx4;  // MFMA acc

#define R32(M) M(0) M(1) M(2) M(3) M(4) M(5) M(6) M(7) M(8) M(9) M(10) M(11) \
  M(12) M(13) M(14) M(15) M(16) M(17) M(18) M(19) M(20) M(21) M(22) M(23) \
  M(24) M(25) M(26) M(27) M(28) M(29) M(30) M(31)

// padded LDS index for h: 4-float pad between the two 128-halves (conflict-free dual-half reads)
#define HIX(j) ((j) + (((j) >> 7) << 2))

// barrier WITHOUT vmcnt drain: only LDS ordering. sched_barrier fences per rule #18.
#define LBAR() do { \
  __builtin_amdgcn_sched_barrier(0); \
  asm volatile("s_waitcnt lgkmcnt(0)" ::: "memory"); \
  __builtin_amdgcn_s_barrier(); \
  __builtin_amdgcn_sched_barrier(0); \
} while (0)

// ================= prep: norms / bf16 conversions / transposes / biases / kNN margins =================
__global__ __launch_bounds__(256) void prep_kernel(
    const int* __restrict__ x,
    const float* __restrict__ emb, const float* __restrict__ demb,
    const float* __restrict__ W_ih,
    const float* __restrict__ Wq, const float* __restrict__ Wk, const float* __restrict__ Wv,
    const float* __restrict__ b_ih, const float* __restrict__ b_hh,
    const float* __restrict__ bq, const float* __restrict__ bk, const float* __restrict__ bv,
    float* __restrict__ dnscale, ushort* __restrict__ demb16, ushort* __restrict__ a16,
    float* __restrict__ wiht, float* __restrict__ wqkvt,
    float* __restrict__ biasih, float* __restrict__ bqkv,
    float* __restrict__ qmargin, u64* __restrict__ packed2)
{
  int blk = blockIdx.x, tid = threadIdx.x;
  if (blk < 5000) {                       // 1/max(||demb_row||, eps)
    int row = blk * 4 + (tid >> 6);
    int lane = tid & 63;
    float2 d = *(const float2*)(demb + (size_t)row * 128 + lane * 2);
    float s = d.x * d.x + d.y * d.y;
    for (int off = 32; off; off >>= 1) s += __shfl_xor(s, off);
    if (lane == 0) dnscale[row] = 1.0f / fmaxf(sqrtf(s), 1e-8f);
  } else if (blk < 6250) {                // demb -> bf16
    size_t base = ((size_t)(blk - 5000) * 256 + tid) * 8;
    float4 f1 = *(const float4*)(demb + base);
    float4 f2 = *(const float4*)(demb + base + 4);
    uint4 o;
    o.x = (uint)f2bf(f1.x) | ((uint)f2bf(f1.y) << 16);
    o.y = (uint)f2bf(f1.z) | ((uint)f2bf(f1.w) << 16);
    o.z = (uint)f2bf(f2.x) | ((uint)f2bf(f2.y) << 16);
    o.w = (uint)f2bf(f2.z) | ((uint)f2bf(f2.w) << 16);
    *(uint4*)(demb16 + base) = o;
  } else if (blk < 6506) {                // emb[x] rows -> bf16 (initial_embs, pre-posenc)
    int idx = (blk - 6250) * 256 + tid;   // < 65536
    int m = idx >> 4, seg = idx & 15;
    const float* src = emb + (size_t)x[m] * 128 + seg * 8;
    float4 f1 = *(const float4*)(src);
    float4 f2 = *(const float4*)(src + 4);
    uint4 o;
    o.x = (uint)f2bf(f1.x) | ((uint)f2bf(f1.y) << 16);
    o.y = (uint)f2bf(f1.z) | ((uint)f2bf(f1.w) << 16);
    o.z = (uint)f2bf(f2.x) | ((uint)f2bf(f2.y) << 16);
    o.w = (uint)f2bf(f2.z) | ((uint)f2bf(f2.w) << 16);
    *(uint4*)(a16 + (size_t)m * 128 + seg * 8) = o;
  } else if (blk < 7018) {                // W_ih (1024,128) -> [e][r]
    int f = (blk - 6506) * 256 + tid;
    int r = f >> 7, e = f & 127;
    wiht[e * 1024 + r] = W_ih[f];
  } else if (blk < 7786) {                // Wq/Wk/Wv (256,256) -> [e][w*256+r]
    int f = (blk - 7018) * 256 + tid;
    int w = f >> 16; int rem = f & 65535;
    int r = rem >> 8, e = rem & 255;
    const float* src = (w == 0) ? Wq : (w == 1) ? Wk : Wv;
    wqkvt[e * 768 + w * 256 + r] = src[rem];
  } else if (blk < 7790) {
    int idx = (blk - 7786) * 256 + tid;
    if (idx < 1024) biasih[idx] = b_ih[idx] + b_hh[idx];
  } else if (blk < 7793) {
    int idx = (blk - 7790) * 256 + tid;
    if (idx < 768) {
      int w = idx >> 8; int r = idx & 255;
      const float* src = (w == 0) ? bq : (w == 1) ? bk : bv;
      bqkv[idx] = src[r];
    }
  } else {                                // kNN margin per query row + zero-row seeds
    int row = (blk - 7793) * 4 + (tid >> 6);   // 1024 blocks -> 4096 rows
    int lane = tid & 63;
    float2 d = *(const float2*)(emb + (size_t)x[row] * 128 + lane * 2);
    float s = d.x * d.x + d.y * d.y;
    for (int off = 32; off; off >>= 1) s += __shfl_xor(s, off);
    if (lane == 0) {
      if (s == 0.f) {
        qmargin[row] = -1e30f;            // sentinel: thr = best+1e30 -> no hits ever
        // all sims exactly +0 -> argmax = first index (n=0), exact
        packed2[row] = ((u64)fkey(0.0f) << 32) | 0xFFFFFFFFull;
      } else {
        // PROVABLE bound: |sim_bf16 - sim_exact| <= 2*2^-8*||q|| (q AND d rounding,
        // Cauchy-Schwarz) ~= 0.0157||q||; 0.017||q|| adds fp32-accum slack.
        qmargin[row] = 0.017f * sqrtf(s) + 1e-5f;
      }
    }
  }
}

// ================= xW = (emb[x]+posenc) @ W_ih^T + (b_ih+b_hh) =================
__global__ __launch_bounds__(256) void xw_kernel(
    const int* __restrict__ x, const float* __restrict__ emb,
    const float* __restrict__ wiht, const float* __restrict__ biasih,
    float* __restrict__ xW)
{
  __shared__ __align__(16) float At[128 * 16];   // [e][m]
  int blk = blockIdx.x, tid = threadIdx.x;
  int m0 = blk * 16;
  for (int c = 0; c < 8; ++c) {
    int idx = c * 256 + tid;
    int mm = idx >> 7, e = idx & 127;
    int m = m0 + mm;
    int bcol = m & 63;                 // PositionalEncoding indexed by BATCH (faithful quirk)
    int xv = x[m];
    float val = emb[(size_t)xv * 128 + e];
    int j = e >> 1;
    float arg = (float)bcol * __expf((float)j * -0.14391157f);  // exp(-j*ln(10000)/64)
    val += (e & 1) ? cosf(arg) : sinf(arg);
    At[e * 16 + mm] = val;
  }
  __syncthreads();
  int quad = tid >> 6, l = tid & 63;
  for (int rp = 0; rp < 4; ++rp) {
    int r = rp * 256 + l * 4;
    float acc[4][4] = {};
    for (int e = 0; e < 128; ++e) {
      float4 wv4 = *(const float4*)(wiht + e * 1024 + r);
      float4 av4 = *(const float4*)(At + e * 16 + quad * 4);
      float am[4] = {av4.x, av4.y, av4.z, av4.w};
      float wr4[4] = {wv4.x, wv4.y, wv4.z, wv4.w};
      #pragma unroll
      for (int mi = 0; mi < 4; ++mi)
        #pragma unroll
        for (int ri = 0; ri < 4; ++ri)
          acc[mi][ri] += am[mi] * wr4[ri];
    }
    float4 bv4 = *(const float4*)(biasih + r);
    #pragma unroll
    for (int mi = 0; mi < 4; ++mi) {
      size_t m = (size_t)(m0 + quad * 4 + mi);
      float4 o;
      o.x = acc[mi][0] + bv4.x; o.y = acc[mi][1] + bv4.y;
      o.z = acc[mi][2] + bv4.z; o.w = acc[mi][3] + bv4.w;
      *(float4*)(xW + m * 1024 + r) = o;
    }
  }
}

// ================= FUSED lstm + knn (ROUND-13 = exact round-9 restore, the best
// measured config: total 580.9us, fused 233us). Round-12's direct-global B was
// refuted (413us: staging IS the coalescing+reuse mechanism — one coalesced
// L2 fetch per block vs 8x redundant scattered per-wave loads). Round-11's
// residency-sized grid also refuted (247us: knn throughput scales with wave
// slots; halving slots doubles the phase). blocks 0-255 = lstm (round-4 body),
// blocks 256-767 = knn (round-7 two-sweep @512 threads: s = wave-index bit). =================
__global__ __launch_bounds__(512, 2) void lstm_knn_kernel(
    const int* __restrict__ lengths, const float* __restrict__ Whh,
    const float* __restrict__ xW, float* __restrict__ lstm_out,
    u64* __restrict__ hx, u64* __restrict__ hxm,
    const ushort* __restrict__ a16, const ushort* __restrict__ demb16,
    const float* __restrict__ dnscale, const float* __restrict__ qmargin,
    u64* __restrict__ packed, uint* __restrict__ hitcnts, uint* __restrict__ ohitcnt,
    uint* __restrict__ hitbuf, uint* __restrict__ ovbuf,
    const int* __restrict__ x, const float* __restrict__ emb,
    const float* __restrict__ demb, u64* __restrict__ packed2)
{
  __shared__ __align__(16) float h_sh[264];      // lstm: 2x128 + pad
  __shared__ float part_sh[256];                 // lstm
  __shared__ __align__(16) ushort b_sh[2][64 * 144];  // knn tile dbuf
  __shared__ uint lcnt;                          // knn
  int tid = threadIdx.x;

  if (blockIdx.x < 256) {
    // ==================== LSTM body (exact round-4) ====================
    int blk = blockIdx.x;
    int b = blk & 63, q = blk >> 6;          // item b blocks {b,64+b,128+b,192+b}
    int row_local = tid >> 1, half = tid & 1;
    int gate = row_local >> 6, jloc = row_local & 63;
    int grow = gate * 256 + q * 64 + jloc;
    const float4* wp4 = (const float4*)(Whh + (size_t)grow * 256 + half * 128);
#define WDECL(i) float4 tt##i = wp4[i]; \
  float w##i##x = tt##i.x, w##i##y = tt##i.y, w##i##z = tt##i.z, w##i##w = tt##i.w;
    R32(WDECL)
    // pin: asm-produced values cannot be rematerialized -> loads can't sink into the loop
#define WPIN(i) asm volatile("" : "+v"(w##i##x), "+v"(w##i##y), "+v"(w##i##z), "+v"(w##i##w));
    R32(WPIN)
    int len = lengths[b];
    if (tid < 256) h_sh[HIX(tid)] = 0.f;
    float cval = 0.f;
    // poller mapping: tid in [320,512) -> the 192 remote j (skip own quarter)
    int prm = tid - 320;
    int jr = (prm < q * 64) ? prm : prm + 64;
    bool fast_ok = true;
    int j1 = q * 64 + (tid - 64);            // wave-1 deferred-store lane -> j
    // xW preload for t=0 (wave0)
    float xw0 = 0.f, xw1 = 0.f, xw2 = 0.f, xw3 = 0.f;
    if (tid < 64) {
      const float* xwrow = xW + ((size_t)0 * 64 + b) * 1024 + q * 64 + tid;
      xw0 = xwrow[0]; xw1 = xwrow[256]; xw2 = xwrow[512]; xw3 = xwrow[768];
    }
    __syncthreads();
    for (int t = 0; t < len; ++t) {
      // prefetch xW(t+1) (wave0): retires under matmul+phase1
      float nx0 = 0.f, nx1 = 0.f, nx2 = 0.f, nx3 = 0.f;
      if (tid < 64 && t + 1 < len) {
        const float* xwrow = xW + ((size_t)(t + 1) * 64 + b) * 1024 + q * 64 + tid;
        nx0 = xwrow[0]; nx1 = xwrow[256]; nx2 = xwrow[512]; nx3 = xwrow[768];
      }
      // wave1: snapshot h(t-1) BEFORE wave0 overwrites it (pre-barrier = race-free)
      float hprev = 0.f;
      if (tid >= 64 && tid < 128 && t > 0) hprev = h_sh[HIX(j1)];
      const float4* h4 = (const float4*)(h_sh + half * 132);
      float a[4] = {0.f, 0.f, 0.f, 0.f};
#define WACC(i) { float4 hv_ = h4[i]; \
    a[(i) & 3] += w##i##x * hv_.x + w##i##y * hv_.y + w##i##z * hv_.z + w##i##w * hv_.w; }
      R32(WACC)
      float acc = (a[0] + a[2]) + (a[1] + a[3]);
      acc += __shfl_xor(acc, 1);             // combine the two half-rows in-register
      if (!half) part_sh[row_local] = acc;
      LBAR();
      if (tid < 64) {
        // -------- phase 2 (wave 0): gates -> h, publish mirror + authoritative --------
        float gi = part_sh[tid]       + xw0;
        float gf = part_sh[64 + tid]  + xw1;
        float gg = part_sh[128 + tid] + xw2;
        float go = part_sh[192 + tid] + xw3;
        float ii = 1.f / (1.f + __expf(-gi));
        float ff = 1.f / (1.f + __expf(-gf));
        float oo = 1.f / (1.f + __expf(-go));
        float tg = 1.f - 2.f / (1.f + __expf(2.f * gg));
        cval = ff * cval + ii * tg;
        float tc = 1.f - 2.f / (1.f + __expf(2.f * cval));
        float hv = oo * tc;
        int j = q * 64 + tid;
        union { float f; uint u; } cu; cu.f = hv;
        u64 pk = ((u64)cu.u << 32) | (u64)(uint)(t + 1);
        size_t slot = ((size_t)((t + 1) & 1) * 64 + b) * 256 + j;
        // same-slot ordering guard: drain all stores older than the 4 prefetch loads
        __builtin_amdgcn_sched_barrier(0);
        asm volatile("s_waitcnt vmcnt(4)" ::: "memory");
        asm volatile("global_store_dwordx2 %0, %1, off"
                     :: "v"(hxm + slot), "v"(pk) : "memory");
        __hip_atomic_store(hx + slot, pk, __ATOMIC_RELAXED, __HIP_MEMORY_SCOPE_AGENT);
        h_sh[HIX(j)] = hv;                   // own quarter stays local
        xw0 = nx0; xw1 = nx1; xw2 = nx2; xw3 = nx3;
      } else if (tid < 128) {
        // -------- wave 1: deferred lstm_out store (one iter late; no in-kernel reader) --------
        if (t > 0) lstm_out[((size_t)b * 64 + (t - 1)) * 256 + j1] = hprev;
      } else if (tid >= 320 && t + 1 < len) {
        // -------- pollers (waves 5-7): fetch partners' h(t+1), overlapped with phase 2 --------
        size_t slot = ((size_t)((t + 1) & 1) * 64 + b) * 256 + jr;
        uint want = (uint)(t + 1);
        u64 v = 0;
        bool got = false;
        if (fast_ok) {
          const u64* ms = hxm + slot;
          for (int tries = 0; tries < 32; ++tries) {
            asm volatile("global_load_dwordx2 %0, %1, off sc0\n\t"
                         "s_waitcnt vmcnt(0)"
                         : "=&v"(v) : "v"(ms) : "memory");
            if ((uint)v == want) { got = true; break; }
          }
          if (!got && t > 0) fast_ok = false;   // sticky fallback; t==0 may be launch skew
        }
        if (!got) {
          const u64* as = hx + slot;            // authoritative, published in-phase by wave0
          int guard = 0;
          while (true) {
            v = __hip_atomic_load(as, __ATOMIC_RELAXED, __HIP_MEMORY_SCOPE_AGENT);
            if ((uint)v == want || ++guard > (1 << 24)) break;
          }
        }
        union { uint u; float f; } cv; cv.u = (uint)(v >> 32);
        h_sh[HIX(jr)] = cv.f;
      }
      LBAR();                                // h_sh (own + remote) complete before next matmul
    }
    // final lstm_out row (wave1 covered only up to t=len-2)
    if (tid >= 64 && tid < 128) {
      float hl = h_sh[HIX(j1)];
      lstm_out[((size_t)b * 64 + (len - 1)) * 256 + j1] = hl;
    }
    return;
  }

  // ==================== kNN body (round-7 two-sweep, 512-thread mapping) ====================
  int kb = blockIdx.x - 256;
  int chunk = kb & 15, mt = kb >> 4;       // 16 chunks x 32 m-tiles
  int w8 = tid >> 6;                       // wave 0..7
  int s = w8 >> 2, wv2 = w8 & 3;           // s-slice + quarter (was s-loop + 4 waves)
  int lane = tid & 63;
  int col = lane & 15, quad = lane >> 4;
  int M0 = mt * 128;
  if (tid == 0) lcnt = 0;
  short8 afrag[4];
  {
    int mrow = M0 + s * 64 + wv2 * 16 + col;
    #pragma unroll
    for (int kf = 0; kf < 4; ++kf)
      afrag[kf] = *(const short8*)(a16 + (size_t)mrow * 128 + kf * 32 + quad * 8);
  }
  float best[4] = {-1e30f, -1e30f, -1e30f, -1e30f};
  int bidx[4] = {};
  int nbase = chunk * 1250, nend = nbase + 1250;
  const int niter = 20;                    // ceil(1250/64)
  int srow = tid >> 4, sseg = tid & 15;    // srow 0..31: stage 32 rows/pass, 2 passes
  uint4 stg[2]; float scr[4];

  // ================== SWEEP A: pure argmax ==================
  #pragma unroll
  for (int p = 0; p < 2; ++p) {
    int n = nbase + p * 32 + srow;
    uint4 v = {0u,0u,0u,0u};
    if (n < nend) v = *(const uint4*)(demb16 + (size_t)n * 128 + sseg * 8);
    stg[p] = v;
  }
  #pragma unroll
  for (int ns = 0; ns < 4; ++ns) {
    int n = nbase + ns * 16 + col;
    scr[ns] = (n < nend) ? dnscale[n] : 0.f;
  }
  for (int it = 0; it < niter; ++it) {
    int n0 = nbase + it * 64;
    ushort* bsh = b_sh[it & 1];
    #pragma unroll
    for (int p = 0; p < 2; ++p)
      *(uint4*)(&bsh[(p * 32 + srow) * 144 + sseg * 8]) = stg[p];
    float mysc[4] = {scr[0], scr[1], scr[2], scr[3]};
    __syncthreads();
    if (it + 1 < niter) {                  // prefetch next tile while computing this one
      int nb = n0 + 64;
      #pragma unroll
      for (int p = 0; p < 2; ++p) {
        int n = nb + p * 32 + srow;
        uint4 v = {0u,0u,0u,0u};
        if (n < nend) v = *(const uint4*)(demb16 + (size_t)n * 128 + sseg * 8);
        stg[p] = v;
      }
      #pragma unroll
      for (int ns = 0; ns < 4; ++ns) {
        int n = nb + ns * 16 + col;
        scr[ns] = (n < nend) ? dnscale[n] : 0.f;
      }
    }
    #pragma unroll
    for (int ns = 0; ns < 4; ++ns) {
      short8 bfr[4];
      #pragma unroll
      for (int kf = 0; kf < 4; ++kf)
        bfr[kf] = *(const short8*)(&bsh[(ns * 16 + col) * 144 + kf * 32 + quad * 8]);
      int n = n0 + ns * 16 + col;
      float sc = mysc[ns];
      bool valid = (n < nend);
      floatx4 acc = {0.f, 0.f, 0.f, 0.f};
      #pragma unroll
      for (int kf = 0; kf < 4; ++kf)
        acc = __builtin_amdgcn_mfma_f32_16x16x32_bf16(afrag[kf], bfr[kf], acc, 0, 0, 0);
      #pragma unroll
      for (int r = 0; r < 4; ++r) {          // D[row=quad*4+r][col=lane&15]
        float sim = acc[r] * sc;
        if (valid && sim > best[r]) { best[r] = sim; bidx[r] = n; }
      }
    }
  }
  // chunk-final per-row best (butterfly over the 16 col lanes) + global argmax output
  float thr[4];
  #pragma unroll
  for (int r = 0; r < 4; ++r) {
    u64 p = ((u64)fkey(best[r]) << 32) | (u64)(0xFFFFFFFFu - (uint)bidx[r]);
    #pragma unroll
    for (int off = 1; off < 16; off <<= 1) {   // col bits only: stays in row group
      u64 o = shfl_xor_u64(p, off);
      if (o > p) p = o;
    }
    int m = M0 + s * 64 + wv2 * 16 + quad * 4 + r;
    union { uint u; float f; } bu;
    uint k = (uint)(p >> 32);
    bu.u = (k & 0x80000000u) ? (k & 0x7FFFFFFFu) : ~k;   // unfkey
    thr[r] = bu.f - qmargin[m];
    if (col == 0)
      atomicMax((unsigned long long*)&packed[m], (unsigned long long)p);
  }
  __syncthreads();

  // ================== SWEEP B: record candidates >= thr (per-block region) ==================
  uint* myregion = hitbuf + (size_t)kb * BLKCAP;
  uint* ovregion = ovbuf;
  #pragma unroll
  for (int p = 0; p < 2; ++p) {
    int n = nbase + p * 32 + srow;
    uint4 v = {0u,0u,0u,0u};
    if (n < nend) v = *(const uint4*)(demb16 + (size_t)n * 128 + sseg * 8);
    stg[p] = v;
  }
  #pragma unroll
  for (int ns = 0; ns < 4; ++ns) {
    int n = nbase + ns * 16 + col;
    scr[ns] = (n < nend) ? dnscale[n] : 0.f;
  }
  for (int it = 0; it < niter; ++it) {
    int n0 = nbase + it * 64;
    ushort* bsh = b_sh[it & 1];
    #pragma unroll
    for (int p = 0; p < 2; ++p)
      *(uint4*)(&bsh[(p * 32 + srow) * 144 + sseg * 8]) = stg[p];
    float mysc[4] = {scr[0], scr[1], scr[2], scr[3]};
    __syncthreads();
    if (it + 1 < niter) {
      int nb = n0 + 64;
      #pragma unroll
      for (int p = 0; p < 2; ++p) {
        int n = nb + p * 32 + srow;
        uint4 v = {0u,0u,0u,0u};
        if (n < nend) v = *(const uint4*)(demb16 + (size_t)n * 128 + sseg * 8);
        stg[p] = v;
      }
      #pragma unroll
      for (int ns = 0; ns < 4; ++ns) {
        int n = nb + ns * 16 + col;
        scr[ns] = (n < nend) ? dnscale[n] : 0.f;
      }
    }
    #pragma unroll
    for (int ns = 0; ns < 4; ++ns) {
      short8 bfr[4];
      #pragma unroll
      for (int kf = 0; kf < 4; ++kf)
        bfr[kf] = *(const short8*)(&bsh[(ns * 16 + col) * 144 + kf * 32 + quad * 8]);
      int n = n0 + ns * 16 + col;
      float sc = mysc[ns];
      bool valid = (n < nend);
      floatx4 acc = {0.f, 0.f, 0.f, 0.f};
      #pragma unroll
      for (int kf = 0; kf < 4; ++kf)
        acc = __builtin_amdgcn_mfma_f32_16x16x32_bf16(afrag[kf], bfr[kf], acc, 0, 0, 0);
      #pragma unroll
      for (int r = 0; r < 4; ++r) {
        float sim = acc[r] * sc;
        bool hit = valid && (sim >= thr[r]);   // ~2e-3 probability
        u64 mask = __ballot(hit);
        if (mask) {
          uint lcntv = (uint)__popcll(mask);
          int leader = __ffsll((unsigned long long)mask) - 1;
          uint base = 0;
          if (lane == leader) base = atomicAdd(&lcnt, lcntv);   // LDS atomic: fast
          base = (uint)__shfl((int)base, leader);
          if (hit) {
            uint pos = base + (uint)__popcll(mask & ((1ull << lane) - 1ull));
            uint mm = (uint)(M0 + s * 64 + wv2 * 16 + quad * 4 + r);
            uint rec = (mm << 15) | (uint)n;
            if (pos < BLKCAP) {
              myregion[pos] = rec;
            } else {                               // rare spill
              uint op = atomicAdd(ohitcnt, 1u);
              if (op < OVCAP) ovregion[op] = rec;
            }
          }
        }
      }
    }
  }
  __syncthreads();                         // full drain: myregion stores visible block-wide
  if (tid == 0) hitcnts[kb] = lcnt;
  // ================== INLINE RESCORE of this block's own hit region ==================
  uint rcnt = lcnt; if (rcnt > BLKCAP) rcnt = BLKCAP;
  for (uint h = tid; h < rcnt; h += 512) {
    uint rec = myregion[h];
    uint m = rec >> 15, n = rec & 0x7FFFu;
    if (m >= 4096 || n >= NDATA) continue;
    const float* qr = emb + (size_t)x[m] * 128;
    const float* dr = demb + (size_t)n * 128;
    double p = 0.0;
    #pragma unroll 8
    for (int e = 0; e < 128; e += 2) {
      float2 qv = *(const float2*)(qr + e);
      float2 dv = *(const float2*)(dr + e);
      p += (double)qv.x * (double)dv.x + (double)qv.y * (double)dv.y;
    }
    float sx = (float)(p * (double)dnscale[n]);
    u64 key = ((u64)fkey(sx) << 32) | (u64)(0xFFFFFFFFu - n);
    atomicMax((unsigned long long*)&packed2[m], (unsigned long long)key);
  }
}

// ================= fused post: blocks 0-255 qkv projection; 256-271 bf16-winner
// exact fallback; 272-287 overflow-region rescore. =================
__global__ __launch_bounds__(256) void fused_post_kernel(
    const float* __restrict__ lstm_out, const float* __restrict__ wqkvt,
    const float* __restrict__ bqkv, float* __restrict__ qkv,
    const u64* __restrict__ packed, const uint* __restrict__ ohitcnt,
    const uint* __restrict__ ovbuf, const int* __restrict__ x,
    const float* __restrict__ emb, const float* __restrict__ demb,
    const float* __restrict__ dnscale, u64* __restrict__ packed2)
{
  __shared__ __align__(16) float At[256 * 16];   // [e][m] (qkv path)
  int blk = blockIdx.x, tid = threadIdx.x;
  if (blk < 256) {                             // ---- qkv = lstm_out @ W{q,k,v}^T + bias ----
    int m0 = blk * 16;
    for (int c = 0; c < 16; ++c)
      At[tid * 16 + c] = lstm_out[((size_t)m0 + c) * 256 + tid];
    __syncthreads();
    int quad = tid >> 6, l = tid & 63;
    for (int rp = 0; rp < 3; ++rp) {
      int r = rp * 256 + l * 4;
      float acc[4][4] = {};
      for (int e = 0; e < 256; ++e) {
        float4 wv4 = *(const float4*)(wqkvt + (size_t)e * 768 + r);
        float4 av4 = *(const float4*)(At + e * 16 + quad * 4);
        float am[4] = {av4.x, av4.y, av4.z, av4.w};
        float wr4[4] = {wv4.x, wv4.y, wv4.z, wv4.w};
        #pragma unroll
        for (int mi = 0; mi < 4; ++mi)
          #pragma unroll
          for (int ri = 0; ri < 4; ++ri)
            acc[mi][ri] += am[mi] * wr4[ri];
      }
      float4 bv4 = *(const float4*)(bqkv + r);
      #pragma unroll
      for (int mi = 0; mi < 4; ++mi) {
        size_t m = (size_t)(m0 + quad * 4 + mi);
        float4 o;
        o.x = acc[mi][0] + bv4.x; o.y = acc[mi][1] + bv4.y;
        o.z = acc[mi][2] + bv4.z; o.w = acc[mi][3] + bv4.w;
        *(float4*)(qkv + m * 768 + r) = o;
      }
    }
    return;
  }
  if (blk < 272) {                             // ---- guaranteed fallback: bf16 winner exact ----
    uint m = (uint)(blk - 256) * 256 + tid;    // 0..4095
    uint n = 0xFFFFFFFFu - (uint)(packed[m] & 0xFFFFFFFFull);
    if (n < NDATA) {
      const float* qr = emb + (size_t)x[m] * 128;
      const float* dr = demb + (size_t)n * 128;
      double p = 0.0;
      #pragma unroll 8
      for (int e = 0; e < 128; e += 2) {
        float2 qv = *(const float2*)(qr + e);
        float2 dv = *(const float2*)(dr + e);
        p += (double)qv.x * (double)dv.x + (double)qv.y * (double)dv.y;
      }
      float sx = (float)(p * (double)dnscale[n]);
      u64 key = ((u64)fkey(sx) << 32) | (u64)(0xFFFFFFFFu - n);
      atomicMax((unsigned long long*)&packed2[m], (unsigned long long)key);
    }
    return;
  }
  // ---- overflow region rescore (blocks 272-287) ----
  uint cnt = *ohitcnt; if (cnt > OVCAP) cnt = OVCAP;
  for (uint h = (uint)(blk - 272) * 256 + tid; h < cnt; h += 16 * 256) {
    uint rec = ovbuf[h];
    uint m = rec >> 15, n = rec & 0x7FFFu;
    if (m >= 4096 || n >= NDATA) continue;
    const float* qr = emb + (size_t)x[m] * 128;
    const float* dr = demb + (size_t)n * 128;
    double p = 0.0;
    #pragma unroll 8
    for (int e = 0; e < 128; e += 2) {
      float2 qv = *(const float2*)(qr + e);
      float2 dv = *(const float2*)(dr + e);
      p += (double)qv.x * (double)dv.x + (double)qv.y * (double)dv.y;
    }
    float sx = (float)(p * (double)dnscale[n]);
    u64 key = ((u64)fkey(sx) << 32) | (u64)(0xFFFFFFFFu - n);
    atomicMax((unsigned long long*)&packed2[m], (unsigned long long)key);
  }
}

// ================= attention (closest fused in: attn block b needs only
// closest[b], computed here in-register) =================
__global__ __launch_bounds__(256) void attn_kernel(
    const float* __restrict__ qkv, const int* __restrict__ lengths,
    const u64* __restrict__ packed2, const float* __restrict__ demb,
    const float* __restrict__ W_out, const float* __restrict__ b_out,
    float* __restrict__ av)
{
  __shared__ float k_sh[64 * 257];               // stride 257 -> conflict-free row reads
  __shared__ __align__(16) float q_sh[4 * 256];
  __shared__ float wpart[4 * 64];
  __shared__ float wtot[64];
  __shared__ float out_sh[256];
  int b = blockIdx.x, tid = threadIdx.x;
  int wv = tid >> 6, lane = tid & 63;
  int len = lengths[b];
  for (int s = 0; s < 64; ++s)
    k_sh[s * 257 + tid] = qkv[((size_t)b * 64 + s) * 768 + 256 + tid];
  // ---- closest (this block's b only), in-register: same-thread write/read ----
  float clv = 0.f;
  if (tid < 128) {
    float sum = 0.f;
    for (int t = 0; t < 64; ++t) {
      uint low = (uint)(packed2[t * 64 + b] & 0xFFFFFFFFull);
      uint n = 0xFFFFFFFFu - low;
      if (n >= NDATA) n = 0;               // safety clamp: never page-fault
      sum += demb[(size_t)n * 128 + tid];
    }
    clv = sum * (1.0f / 64.0f);
  }
  wpart[tid] = 0.f;
  for (int tq = 0; tq < 16; ++tq) {
    __syncthreads();
    #pragma unroll
    for (int c = 0; c < 4; ++c)
      q_sh[c * 256 + tid] = qkv[((size_t)b * 64 + tq * 4 + c) * 768 + tid];
    __syncthreads();
    const float* krow = k_sh + lane * 257;
    const float* qrow = q_sh + wv * 256;
    float sc = 0.f;
    #pragma unroll 8
    for (int h = 0; h < 256; ++h)
      sc += qrow[h] * krow[h];
    sc *= 0.0625f;                         // 1/sqrt(256)
    bool vs = (lane < len);                // key-position mask
    float scm = vs ? sc : -1e30f;
    float mx = scm;
    for (int off = 32; off; off >>= 1) mx = fmaxf(mx, __shfl_xor(mx, off));
    float e = vs ? __expf(sc - mx) : 0.f;
    float sum = e;
    for (int off = 32; off; off >>= 1) sum += __shfl_xor(sum, off);
    wpart[wv * 64 + lane] += e / sum;
  }
  __syncthreads();
  if (tid < 64)
    wtot[tid] = (wpart[tid] + wpart[64 + tid] + wpart[128 + tid] + wpart[192 + tid]) * (1.0f / 64.0f);
  __syncthreads();
  {
    float acc = 0.f;
    for (int s = 0; s < 64; ++s)
      acc += wtot[s] * qkv[((size_t)b * 64 + s) * 768 + 512 + tid];
    out_sh[tid] = acc;
  }
  __syncthreads();
  if (tid < 128) {
    const float4* wr = (const float4*)(W_out + (size_t)tid * 256);
    float p = b_out[tid];
    #pragma unroll
    for (int c = 0; c < 64; ++c) {
      float4 u = wr[c];
      p += out_sh[c * 4 + 0] * u.x + out_sh[c * 4 + 1] * u.y
         + out_sh[c * 4 + 2] * u.z + out_sh[c * 4 + 3] * u.w;
    }
    av[tid * 64 + b] = p * clv;            // [e][b] for wave-uniform loads later
  }
}

// ================= out[b][i] = av[:,b] . emb_table[i] =================
__global__ __launch_bounds__(256) void final_kernel(
    const float* __restrict__ emb, const float* __restrict__ av,
    float* __restrict__ out)
{
  int i = blockIdx.x * 256 + threadIdx.x;
  if (i >= NITEMS) return;
  const float4* row = (const float4*)(emb + (size_t)i * 128);
  float acc[64];
  #pragma unroll
  for (int bb = 0; bb < 64; ++bb) acc[bb] = 0.f;
  for (int e4 = 0; e4 < 32; ++e4) {
    float4 u = row[e4];
    float wvv[4] = {u.x, u.y, u.z, u.w};
    const float* ab = av + e4 * 4 * 64;    // wave-uniform addresses -> scalar pipe
    #pragma unroll
    for (int j = 0; j < 4; ++j) {
      #pragma unroll
      for (int bb = 0; bb < 64; ++bb)
        acc[bb] += wvv[j] * ab[j * 64 + bb];
    }
  }
  #pragma unroll
  for (int bb = 0; bb < 64; ++bb)
    out[(size_t)bb * NITEMS + i] = acc[bb];
}

// ================= launch =================
extern "C" void kernel_launch(void* const* d_in, const int* in_sizes, int n_in,
                              void* d_out, int out_size, void* d_ws, size_t ws_size,
                              hipStream_t stream)
{
  const int*   x       = (const int*)d_in[0];
  const int*   lengths = (const int*)d_in[1];
  const float* emb     = (const float*)d_in[2];
  const float* demb    = (const float*)d_in[3];
  const float* W_ih    = (const float*)d_in[4];
  const float* W_hh    = (const float*)d_in[5];
  const float* b_ih    = (const float*)d_in[6];
  const float* b_hh    = (const float*)d_in[7];
  const float* Wq      = (const float*)d_in[8];
  const float* bq      = (const float*)d_in[9];
  const float* Wk      = (const float*)d_in[10];
  const float* bk      = (const float*)d_in[11];
  const float* Wv      = (const float*)d_in[12];
  const float* bv      = (const float*)d_in[13];
  const float* W_out   = (const float*)d_in[14];
  const float* b_out   = (const float*)d_in[15];

  char* ws = (char*)d_ws;
  float*  lstm_out = (float*)(ws + OFF_LSTMOUT);
  u64*    hx       = (u64*)(ws + OFF_HX);
  u64*    hxm      = (u64*)(ws + OFF_HXM);
  u64*    packed   = (u64*)(ws + OFF_PACKED);
  u64*    packed2  = (u64*)(ws + OFF_PACKED2);
  uint*   hitcnts  = (uint*)(ws + OFF_HITCNTS);
  uint*   ohitcnt  = (uint*)(ws + OFF_OHITCNT);
  float*  qmargin  = (float*)(ws + OFF_QMARGIN);
  uint*   hitbuf   = (uint*)(ws + OFF_HITBUF);
  uint*   ovbuf    = (uint*)(ws + OFF_OVF);
  float*  xW       = (float*)(ws + OFF_XW);
  float*  qkv      = (float*)(ws + OFF_QKV);
  float*  wiht     = (float*)(ws + OFF_WIHT);
  float*  wqkvt    = (float*)(ws + OFF_WQKVT);
  float*  biasih   = (float*)(ws + OFF_BIASIH);
  float*  bqkv     = (float*)(ws + OFF_BQKV);
  float*  dnscale  = (float*)(ws + OFF_DNSCALE);
  float*  av       = (float*)(ws + OFF_AV);
  ushort* demb16   = (ushort*)(ws + OFF_DEMB16);
  ushort* a16      = (ushort*)(ws + OFF_A16);

  hipMemsetAsync(d_ws, 0, (size_t)MEMSET_BYTES, stream);

  hipLaunchKernelGGL(prep_kernel, dim3(8817), dim3(256), 0, stream,
                     x, emb, demb, W_ih, Wq, Wk, Wv, b_ih, b_hh, bq, bk, bv,
                     dnscale, demb16, a16, wiht, wqkvt, biasih, bqkv,
                     qmargin, packed2);
  hipLaunchKernelGGL(xw_kernel, dim3(256), dim3(256), 0, stream,
                     x, emb, wiht, biasih, xW);
  hipLaunchKernelGGL(lstm_knn_kernel, dim3(768), dim3(512), 0, stream,
                     lengths, W_hh, xW, lstm_out, hx, hxm,
                     a16, demb16, dnscale, qmargin, packed, hitcnts, ohitcnt,
                     hitbuf, ovbuf, x, emb, demb, packed2);
  hipLaunchKernelGGL(fused_post_kernel, dim3(288), dim3(256), 0, stream,
                     lstm_out, wqkvt, bqkv, qkv, packed, ohitcnt, ovbuf,
                     x, emb, demb, dnscale, packed2);
  hipLaunchKernelGGL(attn_kernel, dim3(64), dim3(256), 0, stream,
                     qkv, lengths, packed2, demb, W_out, b_out, av);
  hipLaunchKernelGGL(final_kernel, dim3(196), dim3(256), 0, stream,
                     emb, av, (float*)d_out);
}

// Round 14
// 577.855 us; speedup vs baseline: 1.3163x; 1.0271x over previous
//
#include <hip/hip_runtime.h>

typedef unsigned int uint;
typedef unsigned short ushort;
typedef unsigned long long u64;

#define NITEMS 50000
#define NDATA  20000
#define BLKCAP 4096u          // per-block hit region (uint entries)
#define OVCAP  65536u         // overflow region

// ---------------- ws layout (bytes) ----------------
#define OFF_LSTMOUT   0x0000000ULL  // [64][64][256] f32 = 4 MB   (memset 0: covers t>=len masking)
#define OFF_HX        0x0400000ULL  // u64[2 parity][64 item][256 j] = 256 KB (memset 0: tag 0) — LLC authoritative
#define OFF_HXM       0x0440000ULL  // u64[2 parity][64 item][256 j] = 256 KB (memset 0) — same-XCD L2 mirror
#define OFF_PACKED    0x0480000ULL  // [4096] u64 = 32 KB         (memset 0: argmax identity, bf16 pass)
#define OFF_PACKED2   0x0488000ULL  // [4096] u64 = 32 KB         (memset 0 + prep seeds zero rows)
#define OFF_HITCNTS   0x0490000ULL  // [512] uint                  (memset 0)
#define OFF_OHITCNT   0x0490800ULL  // uint                        (memset 0)
#define MEMSET_BYTES  0x0491000ULL
#define OFF_QMARGIN   0x0491000ULL  // [4096] f32 (margin, or -1e30 sentinel for zero rows)
#define OFF_XW        0x05A0000ULL  // [4096][1024] f32 = 16 MB
#define OFF_QKV       0x15A0000ULL  // [4096][768] f32 = 12 MB (cols: 0-255 q, 256-511 k, 512-767 v)
#define OFF_HITBUF    OFF_QKV       // 512*4096 uints = 8 MB; consumed by knn's INLINE rescore -> dead before qkv writes
#define OFF_WIHT      0x21A0000ULL  // [128][1024] f32 transposed W_ih
#define OFF_WQKVT     0x2220000ULL  // [256][768] f32 transposed Wq|Wk|Wv
#define OFF_BIASIH    0x22E0000ULL  // [1024] f32 (b_ih + b_hh)
#define OFF_BQKV      0x22E1000ULL  // [768] f32
#define OFF_DNSCALE   0x22E2000ULL  // [20000] f32  1/max(norm,eps)
#define OFF_AV        0x22FE000ULL  // [128][64] f32 (transposed: [e][b])
#define OFF_DEMB16    0x2306000ULL  // [20000][128] bf16 = 5.12 MB
#define OFF_A16       0x27E8000ULL  // [4096][128] bf16 = 1 MB  (emb[x], pre-posenc)
#define OFF_OVF       0x28E8000ULL  // [65536] uint overflow region = 256 KB
// end 0x2928000 = 43.2 MB

__device__ __forceinline__ ushort f2bf(float f) {
  union { float f; uint u; } v; v.f = f;
  uint u = v.u;
  return (ushort)((u + 0x7FFFu + ((u >> 16) & 1u)) >> 16);  // RNE
}
__device__ __forceinline__ uint fkey(float f) {  // monotone float->uint
  union { float f; uint u; } v; v.f = f;
  return (v.u & 0x80000000u) ? ~v.u : (v.u | 0x80000000u);
}
__device__ __forceinline__ u64 shfl_xor_u64(u64 v, int off) {
  uint lo = (uint)v, hi = (uint)(v >> 32);
  lo = (uint)__shfl_xor((int)lo, off);
  hi = (uint)__shfl_xor((int)hi, off);
  return ((u64)hi << 32) | (u64)lo;
}

typedef __attribute__((ext_vector_type(8))) short short8;   // 8 bf16 (4 VGPRs)
typedef __attribute__((ext_vector_type(4))) float floatx4;  // MFMA acc

#define R32(M) M(0) M(1) M(2) M(3) M(4) M(5) M(6) M(7) M(8) M(9) M(10) M(11) \
  M(12) M(13) M(14) M(15) M(16) M(17) M(18) M(19) M(20) M(21) M(22) M(23) \
  M(24) M(25) M(26) M(27) M(28) M(29) M(30) M(31)

// padded LDS index for h: 4-float pad between the two 128-halves (conflict-free dual-half reads)
#define HIX(j) ((j) + (((j) >> 7) << 2))

// barrier WITHOUT vmcnt drain: only LDS ordering. sched_barrier fences per rule #18.
#define LBAR() do { \
  __builtin_amdgcn_sched_barrier(0); \
  asm volatile("s_waitcnt lgkmcnt(0)" ::: "memory"); \
  __builtin_amdgcn_s_barrier(); \
  __builtin_amdgcn_sched_barrier(0); \
} while (0)

// ================= prep: norms / bf16 conversions / transposes / biases / kNN margins =================
__global__ __launch_bounds__(256) void prep_kernel(
    const int* __restrict__ x,
    const float* __restrict__ emb, const float* __restrict__ demb,
    const float* __restrict__ W_ih,
    const float* __restrict__ Wq, const float* __restrict__ Wk, const float* __restrict__ Wv,
    const float* __restrict__ b_ih, const float* __restrict__ b_hh,
    const float* __restrict__ bq, const float* __restrict__ bk, const float* __restrict__ bv,
    float* __restrict__ dnscale, ushort* __restrict__ demb16, ushort* __restrict__ a16,
    float* __restrict__ wiht, float* __restrict__ wqkvt,
    float* __restrict__ biasih, float* __restrict__ bqkv,
    float* __restrict__ qmargin, u64* __restrict__ packed2)
{
  int blk = blockIdx.x, tid = threadIdx.x;
  if (blk < 5000) {                       // 1/max(||demb_row||, eps)
    int row = blk * 4 + (tid >> 6);
    int lane = tid & 63;
    float2 d = *(const float2*)(demb + (size_t)row * 128 + lane * 2);
    float s = d.x * d.x + d.y * d.y;
    for (int off = 32; off; off >>= 1) s += __shfl_xor(s, off);
    if (lane == 0) dnscale[row] = 1.0f / fmaxf(sqrtf(s), 1e-8f);
  } else if (blk < 6250) {                // demb -> bf16
    size_t base = ((size_t)(blk - 5000) * 256 + tid) * 8;
    float4 f1 = *(const float4*)(demb + base);
    float4 f2 = *(const float4*)(demb + base + 4);
    uint4 o;
    o.x = (uint)f2bf(f1.x) | ((uint)f2bf(f1.y) << 16);
    o.y = (uint)f2bf(f1.z) | ((uint)f2bf(f1.w) << 16);
    o.z = (uint)f2bf(f2.x) | ((uint)f2bf(f2.y) << 16);
    o.w = (uint)f2bf(f2.z) | ((uint)f2bf(f2.w) << 16);
    *(uint4*)(demb16 + base) = o;
  } else if (blk < 6506) {                // emb[x] rows -> bf16 (initial_embs, pre-posenc)
    int idx = (blk - 6250) * 256 + tid;   // < 65536
    int m = idx >> 4, seg = idx & 15;
    const float* src = emb + (size_t)x[m] * 128 + seg * 8;
    float4 f1 = *(const float4*)(src);
    float4 f2 = *(const float4*)(src + 4);
    uint4 o;
    o.x = (uint)f2bf(f1.x) | ((uint)f2bf(f1.y) << 16);
    o.y = (uint)f2bf(f1.z) | ((uint)f2bf(f1.w) << 16);
    o.z = (uint)f2bf(f2.x) | ((uint)f2bf(f2.y) << 16);
    o.w = (uint)f2bf(f2.z) | ((uint)f2bf(f2.w) << 16);
    *(uint4*)(a16 + (size_t)m * 128 + seg * 8) = o;
  } else if (blk < 7018) {                // W_ih (1024,128) -> [e][r]
    int f = (blk - 6506) * 256 + tid;
    int r = f >> 7, e = f & 127;
    wiht[e * 1024 + r] = W_ih[f];
  } else if (blk < 7786) {                // Wq/Wk/Wv (256,256) -> [e][w*256+r]
    int f = (blk - 7018) * 256 + tid;
    int w = f >> 16; int rem = f & 65535;
    int r = rem >> 8, e = rem & 255;
    const float* src = (w == 0) ? Wq : (w == 1) ? Wk : Wv;
    wqkvt[e * 768 + w * 256 + r] = src[rem];
  } else if (blk < 7790) {
    int idx = (blk - 7786) * 256 + tid;
    if (idx < 1024) biasih[idx] = b_ih[idx] + b_hh[idx];
  } else if (blk < 7793) {
    int idx = (blk - 7790) * 256 + tid;
    if (idx < 768) {
      int w = idx >> 8; int r = idx & 255;
      const float* src = (w == 0) ? bq : (w == 1) ? bk : bv;
      bqkv[idx] = src[r];
    }
  } else {                                // kNN margin per query row + zero-row seeds
    int row = (blk - 7793) * 4 + (tid >> 6);   // 1024 blocks -> 4096 rows
    int lane = tid & 63;
    float2 d = *(const float2*)(emb + (size_t)x[row] * 128 + lane * 2);
    float s = d.x * d.x + d.y * d.y;
    for (int off = 32; off; off >>= 1) s += __shfl_xor(s, off);
    if (lane == 0) {
      if (s == 0.f) {
        qmargin[row] = -1e30f;            // sentinel: thr = best+1e30 -> no hits ever
        // all sims exactly +0 -> argmax = first index (n=0), exact
        packed2[row] = ((u64)fkey(0.0f) << 32) | 0xFFFFFFFFull;
      } else {
        // PROVABLE bound: |sim_bf16 - sim_exact| <= 2*2^-8*||q|| (q AND d rounding,
        // Cauchy-Schwarz) ~= 0.0157||q||; 0.017||q|| adds fp32-accum slack.
        qmargin[row] = 0.017f * sqrtf(s) + 1e-5f;
      }
    }
  }
}

// ================= xW = (emb[x]+posenc) @ W_ih^T + (b_ih+b_hh) =================
__global__ __launch_bounds__(256) void xw_kernel(
    const int* __restrict__ x, const float* __restrict__ emb,
    const float* __restrict__ wiht, const float* __restrict__ biasih,
    float* __restrict__ xW)
{
  __shared__ __align__(16) float At[128 * 16];   // [e][m]
  int blk = blockIdx.x, tid = threadIdx.x;
  int m0 = blk * 16;
  for (int c = 0; c < 8; ++c) {
    int idx = c * 256 + tid;
    int mm = idx >> 7, e = idx & 127;
    int m = m0 + mm;
    int bcol = m & 63;                 // PositionalEncoding indexed by BATCH (faithful quirk)
    int xv = x[m];
    float val = emb[(size_t)xv * 128 + e];
    int j = e >> 1;
    float arg = (float)bcol * __expf((float)j * -0.14391157f);  // exp(-j*ln(10000)/64)
    val += (e & 1) ? cosf(arg) : sinf(arg);
    At[e * 16 + mm] = val;
  }
  __syncthreads();
  int quad = tid >> 6, l = tid & 63;
  for (int rp = 0; rp < 4; ++rp) {
    int r = rp * 256 + l * 4;
    float acc[4][4] = {};
    for (int e = 0; e < 128; ++e) {
      float4 wv4 = *(const float4*)(wiht + e * 1024 + r);
      float4 av4 = *(const float4*)(At + e * 16 + quad * 4);
      float am[4] = {av4.x, av4.y, av4.z, av4.w};
      float wr4[4] = {wv4.x, wv4.y, wv4.z, wv4.w};
      #pragma unroll
      for (int mi = 0; mi < 4; ++mi)
        #pragma unroll
        for (int ri = 0; ri < 4; ++ri)
          acc[mi][ri] += am[mi] * wr4[ri];
    }
    float4 bv4 = *(const float4*)(biasih + r);
    #pragma unroll
    for (int mi = 0; mi < 4; ++mi) {
      size_t m = (size_t)(m0 + quad * 4 + mi);
      float4 o;
      o.x = acc[mi][0] + bv4.x; o.y = acc[mi][1] + bv4.y;
      o.z = acc[mi][2] + bv4.z; o.w = acc[mi][3] + bv4.w;
      *(float4*)(xW + m * 1024 + r) = o;
    }
  }
}

// ================= FUSED lstm + knn (round 14): knn restores round-7's 2-slice
// B-reuse, lost in the round-9 widening. r7: each wave held afrag[2][4] (32
// m-rows) -> per ns, bfr read ONCE feeds 8 MFMAs. r9's port made s a wave bit
// (16 rows/wave) -> same 16 ds_read_b128 feed only 4 MFMAs: 2x the LDS-read/
// MFMA ratio, and LDS reads are ~2/3 of knn (each wave reads the full 16KB
// tile per iter at 85 B/cy). Round 14: 8 waves x 32 rows (2 s-slices at
// stride 128) = 256 rows/block -> 16 m-tiles x 16 chunks = 256 knn blocks.
// Total MFMAs unchanged; total ds_reads, staging, barriers HALVED. Grid =
// 256 lstm + 256 knn = 512 = exact 2-blocks/CU residency (round-11 geometry
// but with the per-slot cost fix it was missing). Hit regions: kb=mt*16+chunk
// (256 regions used, ~640 hits/region << BLKCAP). lstm body byte-identical. =================
__global__ __launch_bounds__(512, 2) void lstm_knn_kernel(
    const int* __restrict__ lengths, const float* __restrict__ Whh,
    const float* __restrict__ xW, float* __restrict__ lstm_out,
    u64* __restrict__ hx, u64* __restrict__ hxm,
    const ushort* __restrict__ a16, const ushort* __restrict__ demb16,
    const float* __restrict__ dnscale, const float* __restrict__ qmargin,
    u64* __restrict__ packed, uint* __restrict__ hitcnts, uint* __restrict__ ohitcnt,
    uint* __restrict__ hitbuf, uint* __restrict__ ovbuf,
    const int* __restrict__ x, const float* __restrict__ emb,
    const float* __restrict__ demb, u64* __restrict__ packed2)
{
  __shared__ __align__(16) float h_sh[264];      // lstm: 2x128 + pad
  __shared__ float part_sh[256];                 // lstm
  __shared__ __align__(16) ushort b_sh[2][64 * 144];  // knn tile dbuf
  __shared__ uint lcnt;                          // knn
  int tid = threadIdx.x;

  if (blockIdx.x < 256) {
    // ==================== LSTM body (exact round-4) ====================
    int blk = blockIdx.x;
    int b = blk & 63, q = blk >> 6;          // item b blocks {b,64+b,128+b,192+b}
    int row_local = tid >> 1, half = tid & 1;
    int gate = row_local >> 6, jloc = row_local & 63;
    int grow = gate * 256 + q * 64 + jloc;
    const float4* wp4 = (const float4*)(Whh + (size_t)grow * 256 + half * 128);
#define WDECL(i) float4 tt##i = wp4[i]; \
  float w##i##x = tt##i.x, w##i##y = tt##i.y, w##i##z = tt##i.z, w##i##w = tt##i.w;
    R32(WDECL)
    // pin: asm-produced values cannot be rematerialized -> loads can't sink into the loop
#define WPIN(i) asm volatile("" : "+v"(w##i##x), "+v"(w##i##y), "+v"(w##i##z), "+v"(w##i##w));
    R32(WPIN)
    int len = lengths[b];
    if (tid < 256) h_sh[HIX(tid)] = 0.f;
    float cval = 0.f;
    // poller mapping: tid in [320,512) -> the 192 remote j (skip own quarter)
    int prm = tid - 320;
    int jr = (prm < q * 64) ? prm : prm + 64;
    bool fast_ok = true;
    int j1 = q * 64 + (tid - 64);            // wave-1 deferred-store lane -> j
    // xW preload for t=0 (wave0)
    float xw0 = 0.f, xw1 = 0.f, xw2 = 0.f, xw3 = 0.f;
    if (tid < 64) {
      const float* xwrow = xW + ((size_t)0 * 64 + b) * 1024 + q * 64 + tid;
      xw0 = xwrow[0]; xw1 = xwrow[256]; xw2 = xwrow[512]; xw3 = xwrow[768];
    }
    __syncthreads();
    for (int t = 0; t < len; ++t) {
      // prefetch xW(t+1) (wave0): retires under matmul+phase1
      float nx0 = 0.f, nx1 = 0.f, nx2 = 0.f, nx3 = 0.f;
      if (tid < 64 && t + 1 < len) {
        const float* xwrow = xW + ((size_t)(t + 1) * 64 + b) * 1024 + q * 64 + tid;
        nx0 = xwrow[0]; nx1 = xwrow[256]; nx2 = xwrow[512]; nx3 = xwrow[768];
      }
      // wave1: snapshot h(t-1) BEFORE wave0 overwrites it (pre-barrier = race-free)
      float hprev = 0.f;
      if (tid >= 64 && tid < 128 && t > 0) hprev = h_sh[HIX(j1)];
      const float4* h4 = (const float4*)(h_sh + half * 132);
      float a[4] = {0.f, 0.f, 0.f, 0.f};
#define WACC(i) { float4 hv_ = h4[i]; \
    a[(i) & 3] += w##i##x * hv_.x + w##i##y * hv_.y + w##i##z * hv_.z + w##i##w * hv_.w; }
      R32(WACC)
      float acc = (a[0] + a[2]) + (a[1] + a[3]);
      acc += __shfl_xor(acc, 1);             // combine the two half-rows in-register
      if (!half) part_sh[row_local] = acc;
      LBAR();
      if (tid < 64) {
        // -------- phase 2 (wave 0): gates -> h, publish mirror + authoritative --------
        float gi = part_sh[tid]       + xw0;
        float gf = part_sh[64 + tid]  + xw1;
        float gg = part_sh[128 + tid] + xw2;
        float go = part_sh[192 + tid] + xw3;
        float ii = 1.f / (1.f + __expf(-gi));
        float ff = 1.f / (1.f + __expf(-gf));
        float oo = 1.f / (1.f + __expf(-go));
        float tg = 1.f - 2.f / (1.f + __expf(2.f * gg));
        cval = ff * cval + ii * tg;
        float tc = 1.f - 2.f / (1.f + __expf(2.f * cval));
        float hv = oo * tc;
        int j = q * 64 + tid;
        union { float f; uint u; } cu; cu.f = hv;
        u64 pk = ((u64)cu.u << 32) | (u64)(uint)(t + 1);
        size_t slot = ((size_t)((t + 1) & 1) * 64 + b) * 256 + j;
        // same-slot ordering guard: drain all stores older than the 4 prefetch loads
        __builtin_amdgcn_sched_barrier(0);
        asm volatile("s_waitcnt vmcnt(4)" ::: "memory");
        asm volatile("global_store_dwordx2 %0, %1, off"
                     :: "v"(hxm + slot), "v"(pk) : "memory");
        __hip_atomic_store(hx + slot, pk, __ATOMIC_RELAXED, __HIP_MEMORY_SCOPE_AGENT);
        h_sh[HIX(j)] = hv;                   // own quarter stays local
        xw0 = nx0; xw1 = nx1; xw2 = nx2; xw3 = nx3;
      } else if (tid < 128) {
        // -------- wave 1: deferred lstm_out store (one iter late; no in-kernel reader) --------
        if (t > 0) lstm_out[((size_t)b * 64 + (t - 1)) * 256 + j1] = hprev;
      } else if (tid >= 320 && t + 1 < len) {
        // -------- pollers (waves 5-7): fetch partners' h(t+1), overlapped with phase 2 --------
        size_t slot = ((size_t)((t + 1) & 1) * 64 + b) * 256 + jr;
        uint want = (uint)(t + 1);
        u64 v = 0;
        bool got = false;
        if (fast_ok) {
          const u64* ms = hxm + slot;
          for (int tries = 0; tries < 32; ++tries) {
            asm volatile("global_load_dwordx2 %0, %1, off sc0\n\t"
                         "s_waitcnt vmcnt(0)"
                         : "=&v"(v) : "v"(ms) : "memory");
            if ((uint)v == want) { got = true; break; }
          }
          if (!got && t > 0) fast_ok = false;   // sticky fallback; t==0 may be launch skew
        }
        if (!got) {
          const u64* as = hx + slot;            // authoritative, published in-phase by wave0
          int guard = 0;
          while (true) {
            v = __hip_atomic_load(as, __ATOMIC_RELAXED, __HIP_MEMORY_SCOPE_AGENT);
            if ((uint)v == want || ++guard > (1 << 24)) break;
          }
        }
        union { uint u; float f; } cv; cv.u = (uint)(v >> 32);
        h_sh[HIX(jr)] = cv.f;
      }
      LBAR();                                // h_sh (own + remote) complete before next matmul
    }
    // final lstm_out row (wave1 covered only up to t=len-2)
    if (tid >= 64 && tid < 128) {
      float hl = h_sh[HIX(j1)];
      lstm_out[((size_t)b * 64 + (len - 1)) * 256 + j1] = hl;
    }
    return;
  }

  // ==================== kNN body (r7 2-slice structure, 8 waves x 32 rows = 256 rows/block) ====================
  int kb = blockIdx.x - 256;               // 0..255
  int chunk = kb & 15, mt = kb >> 4;       // 16 chunks x 16 m-tiles(256 rows)
  int w8 = tid >> 6;                       // wave 0..7
  int lane = tid & 63;
  int col = lane & 15, quad = lane >> 4;
  int M0 = mt * 256;
  if (tid == 0) lcnt = 0;
  short8 afrag[2][4];
  #pragma unroll
  for (int s = 0; s < 2; ++s) {
    int mrow = M0 + s * 128 + w8 * 16 + col;
    #pragma unroll
    for (int kf = 0; kf < 4; ++kf)
      afrag[s][kf] = *(const short8*)(a16 + (size_t)mrow * 128 + kf * 32 + quad * 8);
  }
  float best[2][4] = {{-1e30f,-1e30f,-1e30f,-1e30f},{-1e30f,-1e30f,-1e30f,-1e30f}};
  int bidx[2][4] = {};
  int nbase = chunk * 1250, nend = nbase + 1250;
  const int niter = 20;                    // ceil(1250/64)
  int srow = tid >> 4, sseg = tid & 15;    // srow 0..31: stage 32 rows/pass, 2 passes
  uint4 stg[2]; float scr[4];

  // ================== SWEEP A: pure argmax ==================
  #pragma unroll
  for (int p = 0; p < 2; ++p) {
    int n = nbase + p * 32 + srow;
    uint4 v = {0u,0u,0u,0u};
    if (n < nend) v = *(const uint4*)(demb16 + (size_t)n * 128 + sseg * 8);
    stg[p] = v;
  }
  #pragma unroll
  for (int ns = 0; ns < 4; ++ns) {
    int n = nbase + ns * 16 + col;
    scr[ns] = (n < nend) ? dnscale[n] : 0.f;
  }
  for (int it = 0; it < niter; ++it) {
    int n0 = nbase + it * 64;
    ushort* bsh = b_sh[it & 1];
    #pragma unroll
    for (int p = 0; p < 2; ++p)
      *(uint4*)(&bsh[(p * 32 + srow) * 144 + sseg * 8]) = stg[p];
    float mysc[4] = {scr[0], scr[1], scr[2], scr[3]};
    __syncthreads();
    if (it + 1 < niter) {                  // prefetch next tile while computing this one
      int nb = n0 + 64;
      #pragma unroll
      for (int p = 0; p < 2; ++p) {
        int n = nb + p * 32 + srow;
        uint4 v = {0u,0u,0u,0u};
        if (n < nend) v = *(const uint4*)(demb16 + (size_t)n * 128 + sseg * 8);
        stg[p] = v;
      }
      #pragma unroll
      for (int ns = 0; ns < 4; ++ns) {
        int n = nb + ns * 16 + col;
        scr[ns] = (n < nend) ? dnscale[n] : 0.f;
      }
    }
    #pragma unroll
    for (int ns = 0; ns < 4; ++ns) {
      short8 bfr[4];
      #pragma unroll
      for (int kf = 0; kf < 4; ++kf)
        bfr[kf] = *(const short8*)(&bsh[(ns * 16 + col) * 144 + kf * 32 + quad * 8]);
      int n = n0 + ns * 16 + col;
      float sc = mysc[ns];
      bool valid = (n < nend);
      #pragma unroll
      for (int s = 0; s < 2; ++s) {          // bfr reused for BOTH s-slices (r7 pattern)
        floatx4 acc = {0.f, 0.f, 0.f, 0.f};
        #pragma unroll
        for (int kf = 0; kf < 4; ++kf)
          acc = __builtin_amdgcn_mfma_f32_16x16x32_bf16(afrag[s][kf], bfr[kf], acc, 0, 0, 0);
        #pragma unroll
        for (int r = 0; r < 4; ++r) {        // D[row=quad*4+r][col=lane&15]
          float sim = acc[r] * sc;
          if (valid && sim > best[s][r]) { best[s][r] = sim; bidx[s][r] = n; }
        }
      }
    }
  }
  // chunk-final per-row best (butterfly over the 16 col lanes) + global argmax output
  float thr[2][4];
  #pragma unroll
  for (int s = 0; s < 2; ++s)
    #pragma unroll
    for (int r = 0; r < 4; ++r) {
      u64 p = ((u64)fkey(best[s][r]) << 32) | (u64)(0xFFFFFFFFu - (uint)bidx[s][r]);
      #pragma unroll
      for (int off = 1; off < 16; off <<= 1) {   // col bits only: stays in row group
        u64 o = shfl_xor_u64(p, off);
        if (o > p) p = o;
      }
      int m = M0 + s * 128 + w8 * 16 + quad * 4 + r;
      union { uint u; float f; } bu;
      uint k = (uint)(p >> 32);
      bu.u = (k & 0x80000000u) ? (k & 0x7FFFFFFFu) : ~k;   // unfkey
      thr[s][r] = bu.f - qmargin[m];
      if (col == 0)
        atomicMax((unsigned long long*)&packed[m], (unsigned long long)p);
    }
  __syncthreads();

  // ================== SWEEP B: record candidates >= thr (per-block region) ==================
  uint* myregion = hitbuf + (size_t)kb * BLKCAP;
  uint* ovregion = ovbuf;
  #pragma unroll
  for (int p = 0; p < 2; ++p) {
    int n = nbase + p * 32 + srow;
    uint4 v = {0u,0u,0u,0u};
    if (n < nend) v = *(const uint4*)(demb16 + (size_t)n * 128 + sseg * 8);
    stg[p] = v;
  }
  #pragma unroll
  for (int ns = 0; ns < 4; ++ns) {
    int n = nbase + ns * 16 + col;
    scr[ns] = (n < nend) ? dnscale[n] : 0.f;
  }
  for (int it = 0; it < niter; ++it) {
    int n0 = nbase + it * 64;
    ushort* bsh = b_sh[it & 1];
    #pragma unroll
    for (int p = 0; p < 2; ++p)
      *(uint4*)(&bsh[(p * 32 + srow) * 144 + sseg * 8]) = stg[p];
    float mysc[4] = {scr[0], scr[1], scr[2], scr[3]};
    __syncthreads();
    if (it + 1 < niter) {
      int nb = n0 + 64;
      #pragma unroll
      for (int p = 0; p < 2; ++p) {
        int n = nb + p * 32 + srow;
        uint4 v = {0u,0u,0u,0u};
        if (n < nend) v = *(const uint4*)(demb16 + (size_t)n * 128 + sseg * 8);
        stg[p] = v;
      }
      #pragma unroll
      for (int ns = 0; ns < 4; ++ns) {
        int n = nb + ns * 16 + col;
        scr[ns] = (n < nend) ? dnscale[n] : 0.f;
      }
    }
    #pragma unroll
    for (int ns = 0; ns < 4; ++ns) {
      short8 bfr[4];
      #pragma unroll
      for (int kf = 0; kf < 4; ++kf)
        bfr[kf] = *(const short8*)(&bsh[(ns * 16 + col) * 144 + kf * 32 + quad * 8]);
      int n = n0 + ns * 16 + col;
      float sc = mysc[ns];
      bool valid = (n < nend);
      #pragma unroll
      for (int s = 0; s < 2; ++s) {          // bfr reused for BOTH s-slices
        floatx4 acc = {0.f, 0.f, 0.f, 0.f};
        #pragma unroll
        for (int kf = 0; kf < 4; ++kf)
          acc = __builtin_amdgcn_mfma_f32_16x16x32_bf16(afrag[s][kf], bfr[kf], acc, 0, 0, 0);
        #pragma unroll
        for (int r = 0; r < 4; ++r) {
          float sim = acc[r] * sc;
          bool hit = valid && (sim >= thr[s][r]);   // ~2e-3 probability
          u64 mask = __ballot(hit);
          if (mask) {
            uint lcntv = (uint)__popcll(mask);
            int leader = __ffsll((unsigned long long)mask) - 1;
            uint base = 0;
            if (lane == leader) base = atomicAdd(&lcnt, lcntv);   // LDS atomic: fast
            base = (uint)__shfl((int)base, leader);
            if (hit) {
              uint pos = base + (uint)__popcll(mask & ((1ull << lane) - 1ull));
              uint mm = (uint)(M0 + s * 128 + w8 * 16 + quad * 4 + r);
              uint rec = (mm << 15) | (uint)n;
              if (pos < BLKCAP) {
                myregion[pos] = rec;
              } else {                               // rare spill
                uint op = atomicAdd(ohitcnt, 1u);
                if (op < OVCAP) ovregion[op] = rec;
              }
            }
          }
        }
      }
    }
  }
  __syncthreads();                         // full drain: myregion stores visible block-wide
  if (tid == 0) hitcnts[kb] = lcnt;
  // ================== INLINE RESCORE of this block's own hit region ==================
  uint rcnt = lcnt; if (rcnt > BLKCAP) rcnt = BLKCAP;
  for (uint h = tid; h < rcnt; h += 512) {
    uint rec = myregion[h];
    uint m = rec >> 15, n = rec & 0x7FFFu;
    if (m >= 4096 || n >= NDATA) continue;
    const float* qr = emb + (size_t)x[m] * 128;
    const float* dr = demb + (size_t)n * 128;
    double p = 0.0;
    #pragma unroll 8
    for (int e = 0; e < 128; e += 2) {
      float2 qv = *(const float2*)(qr + e);
      float2 dv = *(const float2*)(dr + e);
      p += (double)qv.x * (double)dv.x + (double)qv.y * (double)dv.y;
    }
    float sx = (float)(p * (double)dnscale[n]);
    u64 key = ((u64)fkey(sx) << 32) | (u64)(0xFFFFFFFFu - n);
    atomicMax((unsigned long long*)&packed2[m], (unsigned long long)key);
  }
}

// ================= fused post: blocks 0-255 qkv projection; 256-271 bf16-winner
// exact fallback; 272-287 overflow-region rescore. =================
__global__ __launch_bounds__(256) void fused_post_kernel(
    const float* __restrict__ lstm_out, const float* __restrict__ wqkvt,
    const float* __restrict__ bqkv, float* __restrict__ qkv,
    const u64* __restrict__ packed, const uint* __restrict__ ohitcnt,
    const uint* __restrict__ ovbuf, const int* __restrict__ x,
    const float* __restrict__ emb, const float* __restrict__ demb,
    const float* __restrict__ dnscale, u64* __restrict__ packed2)
{
  __shared__ __align__(16) float At[256 * 16];   // [e][m] (qkv path)
  int blk = blockIdx.x, tid = threadIdx.x;
  if (blk < 256) {                             // ---- qkv = lstm_out @ W{q,k,v}^T + bias ----
    int m0 = blk * 16;
    for (int c = 0; c < 16; ++c)
      At[tid * 16 + c] = lstm_out[((size_t)m0 + c) * 256 + tid];
    __syncthreads();
    int quad = tid >> 6, l = tid & 63;
    for (int rp = 0; rp < 3; ++rp) {
      int r = rp * 256 + l * 4;
      float acc[4][4] = {};
      for (int e = 0; e < 256; ++e) {
        float4 wv4 = *(const float4*)(wqkvt + (size_t)e * 768 + r);
        float4 av4 = *(const float4*)(At + e * 16 + quad * 4);
        float am[4] = {av4.x, av4.y, av4.z, av4.w};
        float wr4[4] = {wv4.x, wv4.y, wv4.z, wv4.w};
        #pragma unroll
        for (int mi = 0; mi < 4; ++mi)
          #pragma unroll
          for (int ri = 0; ri < 4; ++ri)
            acc[mi][ri] += am[mi] * wr4[ri];
      }
      float4 bv4 = *(const float4*)(bqkv + r);
      #pragma unroll
      for (int mi = 0; mi < 4; ++mi) {
        size_t m = (size_t)(m0 + quad * 4 + mi);
        float4 o;
        o.x = acc[mi][0] + bv4.x; o.y = acc[mi][1] + bv4.y;
        o.z = acc[mi][2] + bv4.z; o.w = acc[mi][3] + bv4.w;
        *(float4*)(qkv + m * 768 + r) = o;
      }
    }
    return;
  }
  if (blk < 272) {                             // ---- guaranteed fallback: bf16 winner exact ----
    uint m = (uint)(blk - 256) * 256 + tid;    // 0..4095
    uint n = 0xFFFFFFFFu - (uint)(packed[m] & 0xFFFFFFFFull);
    if (n < NDATA) {
      const float* qr = emb + (size_t)x[m] * 128;
      const float* dr = demb + (size_t)n * 128;
      double p = 0.0;
      #pragma unroll 8
      for (int e = 0; e < 128; e += 2) {
        float2 qv = *(const float2*)(qr + e);
        float2 dv = *(const float2*)(dr + e);
        p += (double)qv.x * (double)dv.x + (double)qv.y * (double)dv.y;
      }
      float sx = (float)(p * (double)dnscale[n]);
      u64 key = ((u64)fkey(sx) << 32) | (u64)(0xFFFFFFFFu - n);
      atomicMax((unsigned long long*)&packed2[m], (unsigned long long)key);
    }
    return;
  }
  // ---- overflow region rescore (blocks 272-287) ----
  uint cnt = *ohitcnt; if (cnt > OVCAP) cnt = OVCAP;
  for (uint h = (uint)(blk - 272) * 256 + tid; h < cnt; h += 16 * 256) {
    uint rec = ovbuf[h];
    uint m = rec >> 15, n = rec & 0x7FFFu;
    if (m >= 4096 || n >= NDATA) continue;
    const float* qr = emb + (size_t)x[m] * 128;
    const float* dr = demb + (size_t)n * 128;
    double p = 0.0;
    #pragma unroll 8
    for (int e = 0; e < 128; e += 2) {
      float2 qv = *(const float2*)(qr + e);
      float2 dv = *(const float2*)(dr + e);
      p += (double)qv.x * (double)dv.x + (double)qv.y * (double)dv.y;
    }
    float sx = (float)(p * (double)dnscale[n]);
    u64 key = ((u64)fkey(sx) << 32) | (u64)(0xFFFFFFFFu - n);
    atomicMax((unsigned long long*)&packed2[m], (unsigned long long)key);
  }
}

// ================= attention (closest fused in: attn block b needs only
// closest[b], computed here in-register) =================
__global__ __launch_bounds__(256) void attn_kernel(
    const float* __restrict__ qkv, const int* __restrict__ lengths,
    const u64* __restrict__ packed2, const float* __restrict__ demb,
    const float* __restrict__ W_out, const float* __restrict__ b_out,
    float* __restrict__ av)
{
  __shared__ float k_sh[64 * 257];               // stride 257 -> conflict-free row reads
  __shared__ __align__(16) float q_sh[4 * 256];
  __shared__ float wpart[4 * 64];
  __shared__ float wtot[64];
  __shared__ float out_sh[256];
  int b = blockIdx.x, tid = threadIdx.x;
  int wv = tid >> 6, lane = tid & 63;
  int len = lengths[b];
  for (int s = 0; s < 64; ++s)
    k_sh[s * 257 + tid] = qkv[((size_t)b * 64 + s) * 768 + 256 + tid];
  // ---- closest (this block's b only), in-register: same-thread write/read ----
  float clv = 0.f;
  if (tid < 128) {
    float sum = 0.f;
    for (int t = 0; t < 64; ++t) {
      uint low = (uint)(packed2[t * 64 + b] & 0xFFFFFFFFull);
      uint n = 0xFFFFFFFFu - low;
      if (n >= NDATA) n = 0;               // safety clamp: never page-fault
      sum += demb[(size_t)n * 128 + tid];
    }
    clv = sum * (1.0f / 64.0f);
  }
  wpart[tid] = 0.f;
  for (int tq = 0; tq < 16; ++tq) {
    __syncthreads();
    #pragma unroll
    for (int c = 0; c < 4; ++c)
      q_sh[c * 256 + tid] = qkv[((size_t)b * 64 + tq * 4 + c) * 768 + tid];
    __syncthreads();
    const float* krow = k_sh + lane * 257;
    const float* qrow = q_sh + wv * 256;
    float sc = 0.f;
    #pragma unroll 8
    for (int h = 0; h < 256; ++h)
      sc += qrow[h] * krow[h];
    sc *= 0.0625f;                         // 1/sqrt(256)
    bool vs = (lane < len);                // key-position mask
    float scm = vs ? sc : -1e30f;
    float mx = scm;
    for (int off = 32; off; off >>= 1) mx = fmaxf(mx, __shfl_xor(mx, off));
    float e = vs ? __expf(sc - mx) : 0.f;
    float sum = e;
    for (int off = 32; off; off >>= 1) sum += __shfl_xor(sum, off);
    wpart[wv * 64 + lane] += e / sum;
  }
  __syncthreads();
  if (tid < 64)
    wtot[tid] = (wpart[tid] + wpart[64 + tid] + wpart[128 + tid] + wpart[192 + tid]) * (1.0f / 64.0f);
  __syncthreads();
  {
    float acc = 0.f;
    for (int s = 0; s < 64; ++s)
      acc += wtot[s] * qkv[((size_t)b * 64 + s) * 768 + 512 + tid];
    out_sh[tid] = acc;
  }
  __syncthreads();
  if (tid < 128) {
    const float4* wr = (const float4*)(W_out + (size_t)tid * 256);
    float p = b_out[tid];
    #pragma unroll
    for (int c = 0; c < 64; ++c) {
      float4 u = wr[c];
      p += out_sh[c * 4 + 0] * u.x + out_sh[c * 4 + 1] * u.y
         + out_sh[c * 4 + 2] * u.z + out_sh[c * 4 + 3] * u.w;
    }
    av[tid * 64 + b] = p * clv;            // [e][b] for wave-uniform loads later
  }
}

// ================= out[b][i] = av[:,b] . emb_table[i] =================
__global__ __launch_bounds__(256) void final_kernel(
    const float* __restrict__ emb, const float* __restrict__ av,
    float* __restrict__ out)
{
  int i = blockIdx.x * 256 + threadIdx.x;
  if (i >= NITEMS) return;
  const float4* row = (const float4*)(emb + (size_t)i * 128);
  float acc[64];
  #pragma unroll
  for (int bb = 0; bb < 64; ++bb) acc[bb] = 0.f;
  for (int e4 = 0; e4 < 32; ++e4) {
    float4 u = row[e4];
    float wvv[4] = {u.x, u.y, u.z, u.w};
    const float* ab = av + e4 * 4 * 64;    // wave-uniform addresses -> scalar pipe
    #pragma unroll
    for (int j = 0; j < 4; ++j) {
      #pragma unroll
      for (int bb = 0; bb < 64; ++bb)
        acc[bb] += wvv[j] * ab[j * 64 + bb];
    }
  }
  #pragma unroll
  for (int bb = 0; bb < 64; ++bb)
    out[(size_t)bb * NITEMS + i] = acc[bb];
}

// ================= launch =================
extern "C" void kernel_launch(void* const* d_in, const int* in_sizes, int n_in,
                              void* d_out, int out_size, void* d_ws, size_t ws_size,
                              hipStream_t stream)
{
  const int*   x       = (const int*)d_in[0];
  const int*   lengths = (const int*)d_in[1];
  const float* emb     = (const float*)d_in[2];
  const float* demb    = (const float*)d_in[3];
  const float* W_ih    = (const float*)d_in[4];
  const float* W_hh    = (const float*)d_in[5];
  const float* b_ih    = (const float*)d_in[6];
  const float* b_hh    = (const float*)d_in[7];
  const float* Wq      = (const float*)d_in[8];
  const float* bq      = (const float*)d_in[9];
  const float* Wk      = (const float*)d_in[10];
  const float* bk      = (const float*)d_in[11];
  const float* Wv      = (const float*)d_in[12];
  const float* bv      = (const float*)d_in[13];
  const float* W_out   = (const float*)d_in[14];
  const float* b_out   = (const float*)d_in[15];

  char* ws = (char*)d_ws;
  float*  lstm_out = (float*)(ws + OFF_LSTMOUT);
  u64*    hx       = (u64*)(ws + OFF_HX);
  u64*    hxm      = (u64*)(ws + OFF_HXM);
  u64*    packed   = (u64*)(ws + OFF_PACKED);
  u64*    packed2  = (u64*)(ws + OFF_PACKED2);
  uint*   hitcnts  = (uint*)(ws + OFF_HITCNTS);
  uint*   ohitcnt  = (uint*)(ws + OFF_OHITCNT);
  float*  qmargin  = (float*)(ws + OFF_QMARGIN);
  uint*   hitbuf   = (uint*)(ws + OFF_HITBUF);
  uint*   ovbuf    = (uint*)(ws + OFF_OVF);
  float*  xW       = (float*)(ws + OFF_XW);
  float*  qkv      = (float*)(ws + OFF_QKV);
  float*  wiht     = (float*)(ws + OFF_WIHT);
  float*  wqkvt    = (float*)(ws + OFF_WQKVT);
  float*  biasih   = (float*)(ws + OFF_BIASIH);
  float*  bqkv     = (float*)(ws + OFF_BQKV);
  float*  dnscale  = (float*)(ws + OFF_DNSCALE);
  float*  av       = (float*)(ws + OFF_AV);
  ushort* demb16   = (ushort*)(ws + OFF_DEMB16);
  ushort* a16      = (ushort*)(ws + OFF_A16);

  hipMemsetAsync(d_ws, 0, (size_t)MEMSET_BYTES, stream);

  hipLaunchKernelGGL(prep_kernel, dim3(8817), dim3(256), 0, stream,
                     x, emb, demb, W_ih, Wq, Wk, Wv, b_ih, b_hh, bq, bk, bv,
                     dnscale, demb16, a16, wiht, wqkvt, biasih, bqkv,
                     qmargin, packed2);
  hipLaunchKernelGGL(xw_kernel, dim3(256), dim3(256), 0, stream,
                     x, emb, wiht, biasih, xW);
  hipLaunchKernelGGL(lstm_knn_kernel, dim3(512), dim3(512), 0, stream,
                     lengths, W_hh, xW, lstm_out, hx, hxm,
                     a16, demb16, dnscale, qmargin, packed, hitcnts, ohitcnt,
                     hitbuf, ovbuf, x, emb, demb, packed2);
  hipLaunchKernelGGL(fused_post_kernel, dim3(288), dim3(256), 0, stream,
                     lstm_out, wqkvt, bqkv, qkv, packed, ohitcnt, ovbuf,
                     x, emb, demb, dnscale, packed2);
  hipLaunchKernelGGL(attn_kernel, dim3(64), dim3(256), 0, stream,
                     qkv, lengths, packed2, demb, W_out, b_out, av);
  hipLaunchKernelGGL(final_kernel, dim3(196), dim3(256), 0, stream,
                     emb, av, (float*)d_out);
}